// Round 10
// baseline (1116.918 us; speedup 1.0000x reference)
//
#include <hip/hip_runtime.h>
#include <hip/hip_cooperative_groups.h>

typedef unsigned int u32;
typedef unsigned long long u64;
typedef float f32x4 __attribute__((ext_vector_type(4)));
typedef short short8 __attribute__((ext_vector_type(8)));

// B=64, S=128, D=512, T=64. 4 groups x 16 batches.
// ws byte offsets:
#define OFF_QX  16777216u   // u64[4 groups][2 slots][16 b][256] f32-pairs of q
#define OFF_EX  17563648u   // per-group exchange
#define G_BYTES 73728u
// group layout: HX u64[2][2048] @0 | CX u64[2][2048] @32768 | FH u32 @65536 (32x64B)
//             | FC @67584 (16x64B) | FQ @68608 (32x64B)

#define OFF_OUT_HT  12288u
#define OFF_OUT_ATT 45056u

#define NBLK 192
#define NTHR 512
#define DYN_LDS 145408

__device__ __forceinline__ float fast_rcp(float x) { return __builtin_amdgcn_rcpf(x); }
// tanh = 1 - 2/(e^{2x}+1): graceful at +/-inf (rcp(inf)=0), no clamps needed
__device__ __forceinline__ float tanh5(float x) {
    float e = __expf(2.f * x);
    return 1.f - 2.f * fast_rcp(e + 1.f);
}
__device__ __forceinline__ float sigm_f(float x) { return fast_rcp(1.f + __expf(-x)); }

__device__ __forceinline__ u32 packbf2(float a, float b) {
    u32 ua = __float_as_uint(a); ua += 0x7FFFu + ((ua >> 16) & 1u);
    u32 ub = __float_as_uint(b); ub += 0x7FFFu + ((ub >> 16) & 1u);
    return (ua >> 16) | (ub & 0xFFFF0000u);
}
__device__ __forceinline__ float2 unpackbf2(u32 u) {
    return make_float2(__uint_as_float(u << 16), __uint_as_float(u & 0xFFFF0000u));
}
// split x into bf16-exact hi + residual lo (lo gets bf16-rounded later)
__device__ __forceinline__ float bf16hi(float x, float& lo) {
    u32 u = __float_as_uint(x); u += 0x7FFFu + ((u >> 16) & 1u); u &= 0xFFFF0000u;
    const float h = __uint_as_float(u); lo = x - h; return h;
}

// relaxed agent-scope accessors: per-access cache bypass, no cache-wide inv/wb
__device__ __forceinline__ u64 cload64(const u64* p) {
    return __hip_atomic_load(p, __ATOMIC_RELAXED, __HIP_MEMORY_SCOPE_AGENT);
}
__device__ __forceinline__ void cstore64(u64* p, u64 v) {
    __hip_atomic_store(p, v, __ATOMIC_RELAXED, __HIP_MEMORY_SCOPE_AGENT);
}
__device__ __forceinline__ u32 cload32(const u32* p) {
    return __hip_atomic_load(p, __ATOMIC_RELAXED, __HIP_MEMORY_SCOPE_AGENT);
}
__device__ __forceinline__ void cstore32(u32* p, u32 v) {
    __hip_atomic_store(p, v, __ATOMIC_RELAXED, __HIP_MEMORY_SCOPE_AGENT);
}

union U8 { u32 u[4]; uint4 q; short8 s; };

// ---------------- fallback-only: flag zeroing ----------------
__global__ __launch_bounds__(256) void flagzero_kernel(float* __restrict__ ws) {
    const int tid = threadIdx.x;
    for (int i = tid; i < 320; i += 256) {
        const int g = i / 80, j = i - g * 80;
        char* gb = (char*)ws + OFF_EX + (size_t)g * G_BYTES;
        if (j < 32)      ((u32*)(gb + 65536))[j * 16] = 0u;
        else if (j < 48) ((u32*)(gb + 67584))[(j - 32) * 16] = 0u;
        else             ((u32*)(gb + 68608))[(j - 48) * 16] = 0u;
    }
}

// ---------------- persistent decode: flags+sync, in-block EU GEMM, 16 attn + 32 GRU ----------------
__global__ __launch_bounds__(512, 1) void decode_kernel(
    const float* __restrict__ e_all,
    const float* __restrict__ e_last,
    const float* __restrict__ Wa_w,  const float* __restrict__ Wa_b,
    const float* __restrict__ Va_w,
    const float* __restrict__ Ua_w,  const float* __restrict__ Ua_b,
    const float* __restrict__ W_ih,  const float* __restrict__ W_hh,
    const float* __restrict__ b_ih,  const float* __restrict__ b_hh,
    const float* __restrict__ Wo_w,  const float* __restrict__ Wo_b,
    float* __restrict__ out, float* __restrict__ ws, int fused)
{
    extern __shared__ char smraw[];

    const int tid = threadIdx.x;
    const int bi  = blockIdx.x;
    const int g   = bi / 48, r = bi % 48;
    const int lane = tid & 63, wv = tid >> 6;

    char* gbase = (char*)ws + OFF_EX + (size_t)g * G_BYTES;
    u64* HX = (u64*)gbase;
    u64* CX = (u64*)(gbase + 32768);
    u32* FH = (u32*)(gbase + 65536);
    u32* FC = (u32*)(gbase + 67584);
    u32* FQ = (u32*)(gbase + 68608);

    if (fused) {
        // each block zeroes the flags it PRODUCES, then grid-wide sync
        if (tid == 0) {
            if (r < 16) cstore32(FC + r * 16, 0u);
            else { cstore32(FH + (r - 16) * 16, 0u); cstore32(FQ + (r - 16) * 16, 0u); }
        }
        __threadfence();
        cooperative_groups::this_grid().sync();
    }

    if (r < 16) {
        // ===================== attention block: one per b =====================
        // startup: EU = exp(2*bf16(e_all[b] @ Ua + bias)) computed IN-BLOCK (hi/lo MFMA).
        // EuL layout: [4 cc][128 s][64 pairs] (32 KB/chunk). Scores read cc = it.
        const int bl = r, b = g * 16 + bl;
        u32*   EuL  = (u32*)smraw;                 // 131072 B
        float* eq_s = (float*)(smraw + 131072);    // 512 f32: exp(2*q)
        float* w_s  = (float*)(smraw + 133120);    // 128 (raw exp)
        float* red  = (float*)(smraw + 133632);    // 16
        float* psq  = (float*)(smraw + 133696);    // 8192 B: ctx partials

        const u64* QXR = (const u64*)((char*)ws + OFF_QX + (size_t)g * 65536);
        const int mn = lane & 15, quad = lane >> 4;

        // ---- in-block Uk GEMM -> EU ----
        {
            u32* Ahi = EuL;                 // 128 rows x 32 kp (XOR-swizzled)
            u32* Alo = Ahi + 4096;
            u32* Bhi = Alo + 4096;          // 128 cols x 32 kp
            u32* Blo = Bhi + 4096;          // scratch = EU blocks 0-1 (65536 B)
            const float* eb = e_all + (size_t)b * 65536;

            auto run_chunk = [&](int cc, f32x4* acc) {
                #pragma unroll
                for (int ct = 0; ct < 8; ++ct) acc[ct] = (f32x4){0.f, 0.f, 0.f, 0.f};
                for (int kc = 0; kc < 8; ++kc) {
                    __syncthreads();
                    // stage A: 128 rows x 16 float4 (k = kc*64..+63)
                    for (int i = tid; i < 2048; i += 512) {
                        const int row = i >> 4, q4 = i & 15;
                        const float4 e = *(const float4*)(eb + (size_t)row * 512 + kc * 64 + 4 * q4);
                        float l0, l1, l2, l3;
                        const float h0 = bf16hi(e.x, l0), h1 = bf16hi(e.y, l1);
                        const float h2 = bf16hi(e.z, l2), h3 = bf16hi(e.w, l3);
                        const int sw = (row & 7) << 2;
                        const int k0 = 2 * q4, k1 = 2 * q4 + 1;
                        const int a0 = row * 32 + (((k0 & ~3) ^ sw) | (k0 & 3));
                        const int a1 = row * 32 + (((k1 & ~3) ^ sw) | (k1 & 3));
                        Ahi[a0] = packbf2(h0, h1); Ahi[a1] = packbf2(h2, h3);
                        Alo[a0] = packbf2(l0, l1); Alo[a1] = packbf2(l2, l3);
                    }
                    // stage B: 128 cols x 32 kp
                    for (int i = tid; i < 4096; i += 512) {
                        const int col = i & 127, kp = i >> 7;
                        const float b0 = Ua_w[(size_t)(kc * 64 + 2 * kp) * 512 + cc * 128 + col];
                        const float b1 = Ua_w[(size_t)(kc * 64 + 2 * kp + 1) * 512 + cc * 128 + col];
                        float l0, l1;
                        const float h0 = bf16hi(b0, l0), h1 = bf16hi(b1, l1);
                        const int sw = (col & 7) << 2;
                        const int ad = col * 32 + (((kp & ~3) ^ sw) | (kp & 3));
                        Bhi[ad] = packbf2(h0, h1);
                        Blo[ad] = packbf2(l0, l1);
                    }
                    __syncthreads();
                    #pragma unroll
                    for (int kb = 0; kb < 2; ++kb) {
                        const int arow = wv * 16 + mn;
                        const int fo = (kb * 16 + quad * 4) ^ ((mn & 7) << 2);
                        U8 ah, al;
                        ah.q = *(const uint4*)(Ahi + arow * 32 + fo);
                        al.q = *(const uint4*)(Alo + arow * 32 + fo);
                        #pragma unroll
                        for (int ct = 0; ct < 8; ++ct) {
                            const int bcol = ct * 16 + mn;
                            U8 bh, bl;
                            bh.q = *(const uint4*)(Bhi + bcol * 32 + fo);
                            bl.q = *(const uint4*)(Blo + bcol * 32 + fo);
                            acc[ct] = __builtin_amdgcn_mfma_f32_16x16x32_bf16(al.s, bh.s, acc[ct], 0, 0, 0);
                            acc[ct] = __builtin_amdgcn_mfma_f32_16x16x32_bf16(ah.s, bl.s, acc[ct], 0, 0, 0);
                            acc[ct] = __builtin_amdgcn_mfma_f32_16x16x32_bf16(ah.s, bh.s, acc[ct], 0, 0, 0);
                        }
                    }
                }
            };
            auto write_chunk = [&](int cc, f32x4* acc) {
                #pragma unroll
                for (int ct = 0; ct < 8; ++ct) {
                    const float bias = Ua_b[cc * 128 + ct * 16 + mn];
                    #pragma unroll
                    for (int reg = 0; reg < 4; ++reg) {
                        float lo_;
                        const float ukr = bf16hi(acc[ct][reg] + bias, lo_);   // bf16-round (matches old UKB path)
                        const float ev  = __expf(2.f * ukr);
                        const float ev1 = __shfl_down(ev, 1);
                        if (!(mn & 1)) {
                            const int s = wv * 16 + quad * 4 + reg;
                            EuL[cc * 8192 + s * 64 + ct * 8 + (mn >> 1)] = packbf2(ev, ev1);
                        }
                    }
                }
            };
            f32x4 accA[8], accB[8];
            run_chunk(3, accA); __syncthreads(); write_chunk(3, accA);
            run_chunk(2, accA); __syncthreads(); write_chunk(2, accA);
            run_chunk(1, accA);
            run_chunk(0, accB);
            __syncthreads();              // all waves done reading scratch
            write_chunk(1, accA);         // block 1 (was scratch) now safe to overwrite
            write_chunk(0, accB);
        }

        // E[b] slice into registers (bf16-packed from f32 e_all)
        uint2 ereg[32];
        {
            const int dq = tid & 127, sg = tid >> 7;
            const float* ep = e_all + (size_t)b * 65536;
            #pragma unroll
            for (int si = 0; si < 32; ++si) {
                const float4 e = *(const float4*)(ep + (size_t)(sg * 32 + si) * 512 + 4 * dq);
                ereg[si] = make_uint2(packbf2(e.x, e.y), packbf2(e.z, e.w));
            }
        }
        // Va-derived constants: va2 = -2*Va slices, vaSum = sum over my 32 dims
        const int kl = lane & 15;
        float4 va2a[4], va2b[4];
        float vaSum = 0.f;
        #pragma unroll
        for (int it = 0; it < 4; ++it) {
            const float4 a  = *(const float4*)(Va_w + (it * 16 + kl) * 8);
            const float4 b2 = *(const float4*)(Va_w + (it * 16 + kl) * 8 + 4);
            vaSum += a.x + a.y + a.z + a.w + b2.x + b2.y + b2.z + b2.w;
            va2a[it] = make_float4(-2.f * a.x,  -2.f * a.y,  -2.f * a.z,  -2.f * a.w);
            va2b[it] = make_float4(-2.f * b2.x, -2.f * b2.y, -2.f * b2.z, -2.f * b2.w);
        }
        __syncthreads();   // EU writes visible to all

        for (int t = 0; t < 64; ++t) {
            const int slot = t & 1;
            u64* CxS = CX + slot * 2048;
            const u64* QxS = QXR + slot * 4096;

            // dependency-aware q wait + EQ = exp(2q): wave w needs GRU blocks idx 8w..8w+7
            if (tid < 256) {
                if (lane < 8) {
                    const u32* f = FQ + (wv * 8 + lane) * 16;
                    while (cload32(f) < (u32)(t + 1)) {}
                }
                const u64 v = cload64(QxS + bl * 256 + tid);
                const float q0 = __uint_as_float((u32)v);
                const float q1 = __uint_as_float((u32)(v >> 32));
                ((float2*)eq_s)[tid] = make_float2(__expf(2.f * q0), __expf(2.f * q1));
            }
            __syncthreads();

            // ---- scores: vaSum + sum va2*rcp(EQ*EU+1), then exp ----
            {
                float4 eqa[4], eqb[4];
                const float4* q4 = (const float4*)eq_s;
                #pragma unroll
                for (int it = 0; it < 4; ++it) {
                    eqa[it] = q4[(it * 16 + kl) * 2];  eqb[it] = q4[(it * 16 + kl) * 2 + 1];
                }
                const uint4* ub = (const uint4*)EuL;
                const int sbase = wv * 16 + (lane >> 4);
                #pragma unroll
                for (int sg = 0; sg < 4; ++sg) {
                    const int s = sbase + sg * 4;
                    float acc = vaSum;
                    #pragma unroll
                    for (int it = 0; it < 4; ++it) {
                        const uint4 u = ub[it * 2048 + s * 16 + kl];
                        const float2 u0 = unpackbf2(u.x), u1 = unpackbf2(u.y);
                        const float2 u2 = unpackbf2(u.z), u3 = unpackbf2(u.w);
                        acc = fmaf(va2a[it].x, fast_rcp(fmaf(eqa[it].x, u0.x, 1.f)), acc);
                        acc = fmaf(va2a[it].y, fast_rcp(fmaf(eqa[it].y, u0.y, 1.f)), acc);
                        acc = fmaf(va2a[it].z, fast_rcp(fmaf(eqa[it].z, u1.x, 1.f)), acc);
                        acc = fmaf(va2a[it].w, fast_rcp(fmaf(eqa[it].w, u1.y, 1.f)), acc);
                        acc = fmaf(va2b[it].x, fast_rcp(fmaf(eqb[it].x, u2.x, 1.f)), acc);
                        acc = fmaf(va2b[it].y, fast_rcp(fmaf(eqb[it].y, u2.y, 1.f)), acc);
                        acc = fmaf(va2b[it].z, fast_rcp(fmaf(eqb[it].z, u3.x, 1.f)), acc);
                        acc = fmaf(va2b[it].w, fast_rcp(fmaf(eqb[it].w, u3.y, 1.f)), acc);
                    }
                    acc += __shfl_xor(acc, 1); acc += __shfl_xor(acc, 2);
                    acc += __shfl_xor(acc, 4); acc += __shfl_xor(acc, 8);
                    if (kl == 0) w_s[s] = __expf(acc);   // Va_b: softmax-invariant
                }
            }
            __syncthreads();

            // ---- denom (wave0) overlapped with unnormalized ctx accum from regs (all) ----
            if (tid < 64) {
                float sm = w_s[tid] + w_s[tid + 64];
                #pragma unroll
                for (int off = 32; off > 0; off >>= 1) sm += __shfl_down(sm, off);
                if (tid == 0) red[1] = fast_rcp(sm);
            }
            {
                const int dq = tid & 127, sg = tid >> 7;
                float4 a = {0.f, 0.f, 0.f, 0.f};
                #pragma unroll
                for (int si = 0; si < 32; ++si) {
                    const float wgt = w_s[sg * 32 + si];
                    const float2 e0 = unpackbf2(ereg[si].x), e1 = unpackbf2(ereg[si].y);
                    a.x = fmaf(wgt, e0.x, a.x);
                    a.y = fmaf(wgt, e0.y, a.y);
                    a.z = fmaf(wgt, e1.x, a.z);
                    a.w = fmaf(wgt, e1.y, a.w);
                }
                ((float4*)psq)[sg * 128 + dq] = a;
            }
            __syncthreads();
            if (tid < 128) {
                const float rn = red[1];
                const float4* p4 = (const float4*)psq;
                float4 a = p4[tid], b2 = p4[128 + tid], c2 = p4[256 + tid], d2 = p4[384 + tid];
                const float rx = (a.x + b2.x + c2.x + d2.x) * rn;
                const float ry = (a.y + b2.y + c2.y + d2.y) * rn;
                const float rz = (a.z + b2.z + c2.z + d2.z) * rn;
                const float rw = (a.w + b2.w + c2.w + d2.w) * rn;
                cstore64(CxS + bl * 128 + tid,
                         (u64)packbf2(rx, ry) | ((u64)packbf2(rz, rw) << 32));
            }
            __syncthreads();
            if (tid == 0) cstore32(FC + bl * 16, (u32)(t + 1));
            else if (tid >= 128 && tid < 256)   // ATT write off the FC critical path
                out[OFF_OUT_ATT + ((size_t)b * 64 + t) * 128 + (tid - 128)] = w_s[tid - 128] * red[1];
        }
    } else {
        // ========== GRU block: 16 dims, 16 b, MFMA tiles, weights in B-frag regs ==========
        // waves 0-2: gh | waves 3-5: FC-poll + ctx stage (ph1), gi MFMA (ph2)
        // wave 6: q = h@Wa slice (MFMA) | wave 7: coords
        const int idx = r - 16, d0 = idx * 16;
        u32*   hbu  = (u32*)smraw;                  // [16][260] bf16-pairs (padded)
        u32*   cbu  = (u32*)(smraw + 16640);        // [16][260] ctx staging
        float* gh_s = (float*)(smraw + 33280);      // 768
        float* gi_s = (float*)(smraw + 36352);      // 768
        float* x_s  = (float*)(smraw + 39424);      // 48
        float* wx_s = (float*)(smraw + 39616);      // 144
        float* wo_s = (float*)(smraw + 40192);      // 1536 + 3

        u64* QXW = (u64*)((char*)ws + OFF_QX + (size_t)g * 65536);

        const int mn = lane & 15, quad = lane >> 4;

        // ---- B-fragments: wv 0-2 = gh gates R,Z,N; wv 3-5 = gi gates; wv 6 = Wa cols ----
        short8 bfrag[16];
        float qbias = 0.f;
        if (wv < 3) {
            const float* wrow = W_hh + (size_t)(wv * 512 + d0 + mn) * 512;
            #pragma unroll
            for (int kb = 0; kb < 16; ++kb) {
                const int k0 = kb * 32 + quad * 8;
                U8 tpk;
                #pragma unroll
                for (int c = 0; c < 4; ++c)
                    tpk.u[c] = packbf2(wrow[k0 + 2 * c], wrow[k0 + 2 * c + 1]);
                bfrag[kb] = tpk.s;
            }
        } else if (wv < 6) {
            const float* wrow = W_ih + (size_t)((wv - 3) * 512 + d0 + mn) * 515;
            #pragma unroll
            for (int kb = 0; kb < 16; ++kb) {
                const int k0 = kb * 32 + quad * 8;
                U8 tpk;
                #pragma unroll
                for (int c = 0; c < 4; ++c)
                    tpk.u[c] = packbf2(wrow[k0 + 2 * c], wrow[k0 + 2 * c + 1]);
                bfrag[kb] = tpk.s;
            }
        } else if (wv == 6) {
            // B[k][col=d0+mn] = Wa_w[k][d0+mn]
            #pragma unroll
            for (int kb = 0; kb < 16; ++kb) {
                const int k0 = kb * 32 + quad * 8;
                U8 tpk;
                #pragma unroll
                for (int c = 0; c < 4; ++c)
                    tpk.u[c] = packbf2(Wa_w[(size_t)(k0 + 2 * c) * 512 + d0 + mn],
                                       Wa_w[(size_t)(k0 + 2 * c + 1) * 512 + d0 + mn]);
                bfrag[kb] = tpk.s;
            }
            qbias = Wa_b[d0 + mn];
        }
        if (tid < 144) {
            const int dd = tid / 9, rem = tid - dd * 9, g3 = rem / 3, c = rem - g3 * 3;
            wx_s[tid] = W_ih[(size_t)(g3 * 512 + d0 + dd) * 515 + 512 + c];
        }
        for (int i = tid; i < 1536; i += 512) wo_s[i] = Wo_w[i];
        if (tid < 3) wo_s[1536 + tid] = Wo_b[tid];

        const int gb = tid >> 4, gd = tid & 15;     // gates mapping (tid<256)
        float hold = 0.f, bih[3], bhh[3];
        if (tid < 256) {
            hold = e_last[(size_t)(g * 16 + gb) * 512 + d0 + gd];
            #pragma unroll
            for (int g3 = 0; g3 < 3; ++g3) {
                bih[g3] = b_ih[g3 * 512 + d0 + gd];
                bhh[g3] = b_hh[g3 * 512 + d0 + gd];
            }
        }

        for (int t = 0; t < 64; ++t) {
            const int slot = t & 1;
            const u64* HxS = HX + slot * 2048;
            const u64* CxS = CX + slot * 2048;
            u64* HxW = HX + ((t + 1) & 1) * 2048;

            if (t > 0) {
                // dependency-aware h wait: wave w loads d4 in half (w&1) -> poll those 16 producers
                if (lane < 16) {
                    const u32* f = FH + ((wv & 1) * 16 + lane) * 16;
                    while (cload32(f) < (u32)t) {}
                }
                #pragma unroll
                for (int u = 0; u < 4; ++u) {
                    const int i = tid + 512 * u;
                    const u64 v = cload64(HxS + i);
                    *(u64*)(hbu + (i >> 7) * 260 + (i & 127) * 2) = v;
                }
            } else {
                // t=0: h0 = e_last, staged directly (bf16 pack identical to old prep H0)
                #pragma unroll
                for (int u = 0; u < 4; ++u) {
                    const int i = tid + 512 * u;
                    const float4 ev = *(const float4*)(e_last + (size_t)(g * 16 + (i >> 7)) * 512 + 4 * (i & 127));
                    *(u64*)(hbu + (i >> 7) * 260 + (i & 127) * 2) =
                        (u64)packbf2(ev.x, ev.y) | ((u64)packbf2(ev.z, ev.w) << 32);
                }
            }
            __syncthreads();

            // ---- phase 1: gh (wv0-2) | FC poll + ctx stage (wv3-5) | q (wv6) | coords (wv7)
            if (wv < 3) {
                f32x4 c = {0.f, 0.f, 0.f, 0.f};
                #pragma unroll
                for (int kb = 0; kb < 16; ++kb) {
                    U8 a; a.q = *(const uint4*)(hbu + mn * 260 + kb * 16 + quad * 4);
                    c = __builtin_amdgcn_mfma_f32_16x16x32_bf16(a.s, bfrag[kb], c, 0, 0, 0);
                }
                #pragma unroll
                for (int reg = 0; reg < 4; ++reg)
                    gh_s[((quad * 4 + reg) * 16 + mn) * 3 + wv] = c[reg];
            } else if (wv < 6) {
                if (lane < 16) { const u32* f = FC + lane * 16; while (cload32(f) < (u32)(t + 1)) {} }
                const int thr = (wv - 3) * 64 + lane;
                for (int i = thr; i < 2048; i += 192) {
                    const u64 v = cload64(CxS + i);
                    *(u64*)(cbu + (i >> 7) * 260 + (i & 127) * 2) = v;
                }
            } else if (wv == 6) {
                f32x4 c = {0.f, 0.f, 0.f, 0.f};
                #pragma unroll
                for (int kb = 0; kb < 16; ++kb) {
                    U8 a; a.q = *(const uint4*)(hbu + mn * 260 + kb * 16 + quad * 4);
                    c = __builtin_amdgcn_mfma_f32_16x16x32_bf16(a.s, bfrag[kb], c, 0, 0, 0);
                }
                u64* QxW = QXW + slot * 4096;
                #pragma unroll
                for (int reg = 0; reg < 4; ++reg) {
                    const float q0 = c[reg] + qbias;
                    const float q1 = __shfl_down(q0, 1);
                    if ((mn & 1) == 0)
                        cstore64(QxW + (size_t)(quad * 4 + reg) * 256 + idx * 8 + (mn >> 1),
                                 (u64)__float_as_uint(q0) | ((u64)__float_as_uint(q1) << 32));
                }
                // order QX stores before the flag, no cache-maintenance fence
                asm volatile("s_waitcnt vmcnt(0)" ::: "memory");
                if (lane == 0) cstore32(FQ + idx * 16, (u32)(t + 1));
            } else {
                const int tt = tid - 448, cb = tt >> 2, kl = tt & 3;
                if (t > 0) {
                    float a0 = 0.f, a1 = 0.f, a2 = 0.f;
                    #pragma unroll 4
                    for (int c = 0; c < 64; ++c) {
                        const int p = kl * 64 + c;
                        const float2 hv = unpackbf2(hbu[cb * 260 + p]);
                        const float* w0 = wo_s + 2 * p * 3;
                        a0 = fmaf(hv.x, w0[0], fmaf(hv.y, w0[3], a0));
                        a1 = fmaf(hv.x, w0[1], fmaf(hv.y, w0[4], a1));
                        a2 = fmaf(hv.x, w0[2], fmaf(hv.y, w0[5], a2));
                    }
                    a0 += __shfl_xor(a0, 1); a1 += __shfl_xor(a1, 1); a2 += __shfl_xor(a2, 1);
                    a0 += __shfl_xor(a0, 2); a1 += __shfl_xor(a1, 2); a2 += __shfl_xor(a2, 2);
                    if (kl == 0) {
                        x_s[cb * 3 + 0] = a0 + wo_s[1536];
                        x_s[cb * 3 + 1] = a1 + wo_s[1537];
                        x_s[cb * 3 + 2] = a2 + wo_s[1538];
                    }
                } else if (tt < 48) x_s[tt] = 0.f;
            }
            __syncthreads();

            // ---- phase 2: gi MFMA (wv3-5) | coords out write (idx 0) ----
            if (wv >= 3 && wv < 6) {
                f32x4 c = {0.f, 0.f, 0.f, 0.f};
                #pragma unroll
                for (int kb = 0; kb < 16; ++kb) {
                    U8 a; a.q = *(const uint4*)(cbu + mn * 260 + kb * 16 + quad * 4);
                    c = __builtin_amdgcn_mfma_f32_16x16x32_bf16(a.s, bfrag[kb], c, 0, 0, 0);
                }
                #pragma unroll
                for (int reg = 0; reg < 4; ++reg)
                    gi_s[((quad * 4 + reg) * 16 + mn) * 3 + (wv - 3)] = c[reg];
            } else if (idx == 0 && t > 0 && tid < 48) {
                out[((size_t)(g * 16 + tid / 3) * 64 + (t - 1)) * 3 + tid % 3] = x_s[tid];
            }
            __syncthreads();

            // ---- gates + h update ----
            if (tid < 256) {
                const int ob = (gb * 16 + gd) * 3;
                const float x0 = x_s[gb * 3 + 0], x1 = x_s[gb * 3 + 1], x2 = x_s[gb * 3 + 2];
                const float giR = gi_s[ob + 0] + bih[0]
                                + x0 * wx_s[gd * 9 + 0] + x1 * wx_s[gd * 9 + 1] + x2 * wx_s[gd * 9 + 2];
                const float giZ = gi_s[ob + 1] + bih[1]
                                + x0 * wx_s[gd * 9 + 3] + x1 * wx_s[gd * 9 + 4] + x2 * wx_s[gd * 9 + 5];
                const float giN = gi_s[ob + 2] + bih[2]
                                + x0 * wx_s[gd * 9 + 6] + x1 * wx_s[gd * 9 + 7] + x2 * wx_s[gd * 9 + 8];
                const float ghR = gh_s[ob + 0] + bhh[0];
                const float ghZ = gh_s[ob + 1] + bhh[1];
                const float ghN = gh_s[ob + 2] + bhh[2];
                const float rg = sigm_f(giR + ghR);
                const float zg = sigm_f(giZ + ghZ);
                const float ng = tanh5(giN + rg * ghN);
                const float hnew = (1.f - zg) * ng + zg * hold;
                hold = hnew;
                const float s1 = __shfl_down(hnew, 1);
                const float s2 = __shfl_down(hnew, 2);
                const float s3 = __shfl_down(hnew, 3);
                if ((gd & 3) == 0)
                    cstore64(HxW + gb * 128 + ((d0 + gd) >> 2),
                             (u64)packbf2(hnew, s1) | ((u64)packbf2(s2, s3) << 32));
                if (t == 63)
                    out[OFF_OUT_HT + (size_t)(g * 16 + gb) * 512 + d0 + gd] = hnew;
            }
            __syncthreads();
            if (tid == 0) cstore32(FH + idx * 16, (u32)(t + 1));
        }

        // ---- final: coords(h_64) -> out[:,63] ----
        if (tid < 32) { const u32* f = FH + tid * 16; while (cload32(f) < 64u) {} }
        __syncthreads();
        #pragma unroll
        for (int u = 0; u < 4; ++u) {
            const int i = tid + 512 * u;
            const u64 v = cload64(HX + i);   // slot 0 holds h_64
            *(u64*)(hbu + (i >> 7) * 260 + (i & 127) * 2) = v;
        }
        __syncthreads();
        if (wv >= 6) {
            const int tt = tid - 384, cb = tt >> 3, kl = tt & 7;
            float a0 = 0.f, a1 = 0.f, a2 = 0.f;
            #pragma unroll 4
            for (int c = 0; c < 32; ++c) {
                const int p = kl * 32 + c;
                const float2 hv = unpackbf2(hbu[cb * 260 + p]);
                const float* w0 = wo_s + 2 * p * 3;
                a0 = fmaf(hv.x, w0[0], fmaf(hv.y, w0[3], a0));
                a1 = fmaf(hv.x, w0[1], fmaf(hv.y, w0[4], a1));
                a2 = fmaf(hv.x, w0[2], fmaf(hv.y, w0[5], a2));
            }
            a0 += __shfl_xor(a0, 1); a1 += __shfl_xor(a1, 1); a2 += __shfl_xor(a2, 1);
            a0 += __shfl_xor(a0, 2); a1 += __shfl_xor(a1, 2); a2 += __shfl_xor(a2, 2);
            a0 += __shfl_xor(a0, 4); a1 += __shfl_xor(a1, 4); a2 += __shfl_xor(a2, 4);
            if (kl == 0) {
                x_s[cb * 3 + 0] = a0 + wo_s[1536];
                x_s[cb * 3 + 1] = a1 + wo_s[1537];
                x_s[cb * 3 + 2] = a2 + wo_s[1538];
            }
        }
        __syncthreads();
        if (idx == 0 && tid < 48)
            out[((size_t)(g * 16 + tid / 3) * 64 + 63) * 3 + tid % 3] = x_s[tid];
    }
}

extern "C" void kernel_launch(void* const* d_in, const int* in_sizes, int n_in,
                              void* d_out, int out_size, void* d_ws, size_t ws_size,
                              hipStream_t stream) {
    const float* e_all  = (const float*)d_in[0];
    const float* e_last = (const float*)d_in[1];
    const float* Wa_w   = (const float*)d_in[2];
    const float* Wa_b   = (const float*)d_in[3];
    const float* Ua_w   = (const float*)d_in[4];
    const float* Ua_b   = (const float*)d_in[5];
    const float* Va_w   = (const float*)d_in[6];
    const float* W_ih   = (const float*)d_in[8];
    const float* W_hh   = (const float*)d_in[9];
    const float* b_ih   = (const float*)d_in[10];
    const float* b_hh   = (const float*)d_in[11];
    const float* Wo_w   = (const float*)d_in[12];
    const float* Wo_b   = (const float*)d_in[13];
    float* outp = (float*)d_out;
    float* ws   = (float*)d_ws;

    hipFuncSetAttribute((const void*)decode_kernel,
                        hipFuncAttributeMaxDynamicSharedMemorySize, DYN_LDS);

    int fused = 1;
    void* args[] = { (void*)&e_all, (void*)&e_last, (void*)&Wa_w, (void*)&Wa_b,
                     (void*)&Va_w, (void*)&Ua_w, (void*)&Ua_b,
                     (void*)&W_ih, (void*)&W_hh, (void*)&b_ih, (void*)&b_hh,
                     (void*)&Wo_w, (void*)&Wo_b, (void*)&outp, (void*)&ws,
                     (void*)&fused };
    hipError_t err = hipLaunchCooperativeKernel((void*)decode_kernel, dim3(NBLK), dim3(NTHR),
                                                args, DYN_LDS, stream);
    if (err != hipSuccess) {
        // fallback: tiny flag-zero kernel + plain decode (fused=0, no grid sync)
        hipLaunchKernelGGL(flagzero_kernel, dim3(1), dim3(256), 0, stream, ws);
        hipLaunchKernelGGL(decode_kernel, dim3(NBLK), dim3(NTHR), DYN_LDS, stream,
                           e_all, e_last, Wa_w, Wa_b, Va_w, Ua_w, Ua_b,
                           W_ih, W_hh, b_ih, b_hh, Wo_w, Wo_b, outp, ws, 0);
    }
}

// Round 11
// 914.145 us; speedup vs baseline: 1.2218x; 1.2218x over previous
//
#include <hip/hip_runtime.h>

typedef unsigned int u32;
typedef unsigned long long u64;
typedef float f32x4 __attribute__((ext_vector_type(4)));
typedef short short8 __attribute__((ext_vector_type(8)));

// B=64, S=128, D=512, T=64. 4 groups x 16 batches.
// ws byte offsets:
#define OFF_UKB 0u          // u32[64*128*256] bf16 Uk
#define OFF_QX  16777216u   // u64[4 groups][2 slots][16 b][512] tagged f32 EQ (131072 B/group)
#define OFF_EX  17563648u   // per-group exchange
#define G_BYTES 73728u
// group layout: HX u64[2][2048] @0 | CX u64[2][2048] @32768 | FH u32 @65536 (32x64B)
//             | FC @67584 (16x64B) | FQ @68608 (unused since r11)

#define OFF_OUT_HT  12288u
#define OFF_OUT_ATT 45056u

#define NBLK 192
#define NTHR 512
#define DYN_LDS 145408
#define PREP_LDS 36864

__device__ __forceinline__ float fast_rcp(float x) { return __builtin_amdgcn_rcpf(x); }
// tanh = 1 - 2/(e^{2x}+1): graceful at +/-inf (rcp(inf)=0), no clamps needed
__device__ __forceinline__ float tanh5(float x) {
    float e = __expf(2.f * x);
    return 1.f - 2.f * fast_rcp(e + 1.f);
}
__device__ __forceinline__ float sigm_f(float x) { return fast_rcp(1.f + __expf(-x)); }

__device__ __forceinline__ u32 packbf2(float a, float b) {
    u32 ua = __float_as_uint(a); ua += 0x7FFFu + ((ua >> 16) & 1u);
    u32 ub = __float_as_uint(b); ub += 0x7FFFu + ((ub >> 16) & 1u);
    return (ua >> 16) | (ub & 0xFFFF0000u);
}
__device__ __forceinline__ float2 unpackbf2(u32 u) {
    return make_float2(__uint_as_float(u << 16), __uint_as_float(u & 0xFFFF0000u));
}
// split x into bf16-exact hi + residual lo (lo gets bf16-rounded later)
__device__ __forceinline__ float bf16hi(float x, float& lo) {
    u32 u = __float_as_uint(x); u += 0x7FFFu + ((u >> 16) & 1u); u &= 0xFFFF0000u;
    const float h = __uint_as_float(u); lo = x - h; return h;
}

// relaxed agent-scope accessors: per-access cache bypass, no cache-wide inv/wb
__device__ __forceinline__ u64 cload64(const u64* p) {
    return __hip_atomic_load(p, __ATOMIC_RELAXED, __HIP_MEMORY_SCOPE_AGENT);
}
__device__ __forceinline__ void cstore64(u64* p, u64 v) {
    __hip_atomic_store(p, v, __ATOMIC_RELAXED, __HIP_MEMORY_SCOPE_AGENT);
}
__device__ __forceinline__ u32 cload32(const u32* p) {
    return __hip_atomic_load(p, __ATOMIC_RELAXED, __HIP_MEMORY_SCOPE_AGENT);
}
__device__ __forceinline__ void cstore32(u32* p, u32 v) {
    __hip_atomic_store(p, v, __ATOMIC_RELAXED, __HIP_MEMORY_SCOPE_AGENT);
}

union U8 { u32 u[4]; uint4 q; short8 s; };

// ---------------- prep: Uk GEMM (MFMA, hi/lo bf16 split) + H0 + flags + QX zero ----------------
// grid 1024 x 256. GEMM tile: 64 rows x 64 cols, K=512 in 8 stages of 64 (36KB LDS -> 4 blk/CU).
__global__ __launch_bounds__(256) void prep_kernel(
    const float* __restrict__ e_all, const float* __restrict__ e_last,
    const float* __restrict__ Ua_w,  const float* __restrict__ Ua_b,
    float* __restrict__ ws)
{
    extern __shared__ char pls[];
    u32* Ahi = (u32*)pls;            // [64 rows][36 kp]
    u32* Alo = Ahi + 64 * 36;
    u32* Bhi = Alo + 64 * 36;        // [64 cols][36 kp]
    u32* Blo = Bhi + 64 * 36;

    u32* UKB = (u32*)((char*)ws + OFF_UKB);

    const int blk = blockIdx.x, tid = threadIdx.x;
    const int gtid = blk * 256 + tid, gstride = 1024 * 256;

    // flags zero: 4 groups x 1280 u32 (FH 512 + FC 256 + FQ 512)
    for (int i = gtid; i < 5120; i += gstride) {
        const int g = i / 1280, j = i - g * 1280;
        ((u32*)((char*)ws + OFF_EX + (size_t)g * G_BYTES + 65536))[j] = 0u;
    }
    // QX zero (tags must not alias any step tag >= 1; also kills cross-run leftovers)
    for (int i = gtid; i < 65536; i += gstride)
        ((u64*)((char*)ws + OFF_QX))[i] = 0ull;
    // H0 -> HX slot 0 (u64 = 4 bf16)
    for (int i = gtid; i < 8192; i += gstride) {
        const int g = i >> 11, i2 = i & 2047;
        const float* ep = e_last + ((size_t)(g * 16 + (i2 >> 7)) * 512) + 4 * (i2 & 127);
        u64* HX = (u64*)((char*)ws + OFF_EX + (size_t)g * G_BYTES);
        HX[i2] = (u64)packbf2(ep[0], ep[1]) | ((u64)packbf2(ep[2], ep[3]) << 32);
    }

    // ---- Uk = e_all[8192x512] @ Ua[512x512] + b, MFMA with hi+lo compensation ----
    const int r0 = (blk >> 3) * 64, c0 = (blk & 7) * 64;
    const int lane = tid & 63, wv = tid >> 6;
    const int mn = lane & 15, quad = lane >> 4;

    f32x4 acc[4];
    #pragma unroll
    for (int rg = 0; rg < 4; ++rg) acc[rg] = (f32x4){0.f, 0.f, 0.f, 0.f};

    for (int ks = 0; ks < 8; ++ks) {
        if (ks) __syncthreads();   // protect LDS reuse across stages
        // stage A: 64 rows x 16 float4 (k = ks*64 .. +63)
        for (int i = tid; i < 1024; i += 256) {
            const int row = i >> 4, q4i = i & 15;
            const float4 e = *(const float4*)(e_all + (size_t)(r0 + row) * 512 + ks * 64 + 4 * q4i);
            float l0, l1, l2, l3;
            const float h0 = bf16hi(e.x, l0), h1 = bf16hi(e.y, l1);
            const float h2 = bf16hi(e.z, l2), h3 = bf16hi(e.w, l3);
            Ahi[row * 36 + 2 * q4i]     = packbf2(h0, h1);
            Ahi[row * 36 + 2 * q4i + 1] = packbf2(h2, h3);
            Alo[row * 36 + 2 * q4i]     = packbf2(l0, l1);
            Alo[row * 36 + 2 * q4i + 1] = packbf2(l2, l3);
        }
        // stage B: 32 kp x 64 cols
        for (int i = tid; i < 2048; i += 256) {
            const int col = i & 63, kp = i >> 6;
            const float b0 = Ua_w[(size_t)(ks * 64 + 2 * kp) * 512 + c0 + col];
            const float b1 = Ua_w[(size_t)(ks * 64 + 2 * kp + 1) * 512 + c0 + col];
            float l0, l1;
            const float h0 = bf16hi(b0, l0), h1 = bf16hi(b1, l1);
            Bhi[col * 36 + kp] = packbf2(h0, h1);
            Blo[col * 36 + kp] = packbf2(l0, l1);
        }
        __syncthreads();
        #pragma unroll
        for (int kb = 0; kb < 2; ++kb) {
            const int fo = kb * 16 + quad * 4;
            U8 bh, bl;
            bh.q = *(const uint4*)(Bhi + (wv * 16 + mn) * 36 + fo);
            bl.q = *(const uint4*)(Blo + (wv * 16 + mn) * 36 + fo);
            #pragma unroll
            for (int rg = 0; rg < 4; ++rg) {
                U8 ah, al;
                ah.q = *(const uint4*)(Ahi + (rg * 16 + mn) * 36 + fo);
                al.q = *(const uint4*)(Alo + (rg * 16 + mn) * 36 + fo);
                acc[rg] = __builtin_amdgcn_mfma_f32_16x16x32_bf16(al.s, bh.s, acc[rg], 0, 0, 0);
                acc[rg] = __builtin_amdgcn_mfma_f32_16x16x32_bf16(ah.s, bl.s, acc[rg], 0, 0, 0);
                acc[rg] = __builtin_amdgcn_mfma_f32_16x16x32_bf16(ah.s, bh.s, acc[rg], 0, 0, 0);
            }
        }
    }
    // epilogue: bias + pack pairs (cols mn,mn+1 via shfl) + store
    const int col = c0 + wv * 16 + mn;
    const float bias = Ua_b[col];
    #pragma unroll
    for (int rg = 0; rg < 4; ++rg) {
        #pragma unroll
        for (int reg = 0; reg < 4; ++reg) {
            const float v = acc[rg][reg] + bias;
            const float v1 = __shfl_down(v, 1);
            if (!(mn & 1))
                UKB[(size_t)(r0 + rg * 16 + quad * 4 + reg) * 256 + (col >> 1)] = packbf2(v, v1);
        }
    }
}

// ---------------- persistent decode: per group 16 attn + 32 GRU blocks ----------------
__global__ __launch_bounds__(512, 1) void decode_kernel(
    const float* __restrict__ e_all,
    const float* __restrict__ e_last,
    const float* __restrict__ Wa_w,  const float* __restrict__ Wa_b,
    const float* __restrict__ Va_w,
    const float* __restrict__ W_ih,  const float* __restrict__ W_hh,
    const float* __restrict__ b_ih,  const float* __restrict__ b_hh,
    const float* __restrict__ Wo_w,  const float* __restrict__ Wo_b,
    float* __restrict__ out, float* __restrict__ ws)
{
    extern __shared__ char smraw[];

    const u32* UKB = (const u32*)((char*)ws + OFF_UKB);

    const int tid = threadIdx.x;
    const int bi  = blockIdx.x;
    const int g   = bi / 48, r = bi % 48;
    const int lane = tid & 63, wv = tid >> 6;

    char* gbase = (char*)ws + OFF_EX + (size_t)g * G_BYTES;
    u64* HX = (u64*)gbase;
    u64* CX = (u64*)(gbase + 32768);
    u32* FH = (u32*)(gbase + 65536);
    u32* FC = (u32*)(gbase + 67584);

    if (r < 16) {
        // ===================== attention block: one per b =====================
        // EU = exp(2*Uk) in LDS; EQ = exp(2q) arrives TAGGED from GRU wave 6 (no flag, no drain).
        // tanh(q+Uk) = 1 - 2*rcp(EQ*EU + 1); score = vaSum + sum (-2Va)*rcp(...). No max-sub.
        const int bl = r, b = g * 16 + bl;
        u32*   EuL  = (u32*)smraw;                 // 131072 B: exp(2*Uk[b]) bf16 [128 s][256 pairs]
        float* eq_s = (float*)(smraw + 131072);    // 512 f32: exp(2*q)
        float* w_s  = (float*)(smraw + 133120);    // 128 (raw exp)
        float* red  = (float*)(smraw + 133632);    // 16
        float* psq  = (float*)(smraw + 133696);    // 8192 B: ctx partials

        const u64* QXR = (const u64*)((char*)ws + OFF_QX + (size_t)g * 131072u);

        // stage EU = exp(2*Uk[b]) into LDS once (persistent across all 64 steps)
        {
            const uint4* src = (const uint4*)(UKB + (size_t)b * 32768);
            uint4* dst = (uint4*)EuL;
            #pragma unroll
            for (int i = 0; i < 16; ++i) {
                uint4 u = src[tid + 512 * i];
                float2 p;
                p = unpackbf2(u.x); u.x = packbf2(__expf(2.f * p.x), __expf(2.f * p.y));
                p = unpackbf2(u.y); u.y = packbf2(__expf(2.f * p.x), __expf(2.f * p.y));
                p = unpackbf2(u.z); u.z = packbf2(__expf(2.f * p.x), __expf(2.f * p.y));
                p = unpackbf2(u.w); u.w = packbf2(__expf(2.f * p.x), __expf(2.f * p.y));
                dst[tid + 512 * i] = u;
            }
        }
        // E[b] slice into registers once (bf16-packed from f32 e_all)
        uint2 ereg[32];
        {
            const int dq = tid & 127, sg = tid >> 7;
            const float* ep = e_all + (size_t)b * 65536;
            #pragma unroll
            for (int si = 0; si < 32; ++si) {
                const float4 e = *(const float4*)(ep + (size_t)(sg * 32 + si) * 512 + 4 * dq);
                ereg[si] = make_uint2(packbf2(e.x, e.y), packbf2(e.z, e.w));
            }
        }
        // Va-derived constants: va2 = -2*Va slices, vaSum = sum over my 32 dims
        const int kl = lane & 15;
        float4 va2a[4], va2b[4];
        float vaSum = 0.f;
        #pragma unroll
        for (int it = 0; it < 4; ++it) {
            const float4 a  = *(const float4*)(Va_w + (it * 16 + kl) * 8);
            const float4 b2 = *(const float4*)(Va_w + (it * 16 + kl) * 8 + 4);
            vaSum += a.x + a.y + a.z + a.w + b2.x + b2.y + b2.z + b2.w;
            va2a[it] = make_float4(-2.f * a.x,  -2.f * a.y,  -2.f * a.z,  -2.f * a.w);
            va2b[it] = make_float4(-2.f * b2.x, -2.f * b2.y, -2.f * b2.z, -2.f * b2.w);
        }
        __syncthreads();

        for (int t = 0; t < 64; ++t) {
            const int slot = t & 1;
            const u32 tg = (u32)(t + 1);
            u64* CxS = CX + slot * 2048;
            const u64* QxS = QXR + slot * 8192 + (size_t)bl * 512;

            // tagged EQ: each of tid<256 spins on its own 2 words (data IS the signal)
            if (tid < 256) {
                u64 v0 = cload64(QxS + 2 * tid), v1 = cload64(QxS + 2 * tid + 1);
                while ((u32)(v0 >> 32) != tg) v0 = cload64(QxS + 2 * tid);
                while ((u32)(v1 >> 32) != tg) v1 = cload64(QxS + 2 * tid + 1);
                ((float2*)eq_s)[tid] = make_float2(__uint_as_float((u32)v0),
                                                   __uint_as_float((u32)v1));
            }
            __syncthreads();

            // ---- scores: vaSum + sum va2*rcp(EQ*EU+1), then exp ----
            {
                float4 eqa[4], eqb[4];
                const float4* q4 = (const float4*)eq_s;
                #pragma unroll
                for (int it = 0; it < 4; ++it) {
                    eqa[it] = q4[(it * 16 + kl) * 2];  eqb[it] = q4[(it * 16 + kl) * 2 + 1];
                }
                const int sbase = wv * 16 + (lane >> 4);
                #pragma unroll
                for (int sg = 0; sg < 4; ++sg) {
                    const int s = sbase + sg * 4;
                    const uint4* uk4 = (const uint4*)EuL + (size_t)s * 64;
                    float acc = vaSum;
                    #pragma unroll
                    for (int it = 0; it < 4; ++it) {
                        const uint4 u = uk4[it * 16 + kl];
                        const float2 u0 = unpackbf2(u.x), u1 = unpackbf2(u.y);
                        const float2 u2 = unpackbf2(u.z), u3 = unpackbf2(u.w);
                        acc = fmaf(va2a[it].x, fast_rcp(fmaf(eqa[it].x, u0.x, 1.f)), acc);
                        acc = fmaf(va2a[it].y, fast_rcp(fmaf(eqa[it].y, u0.y, 1.f)), acc);
                        acc = fmaf(va2a[it].z, fast_rcp(fmaf(eqa[it].z, u1.x, 1.f)), acc);
                        acc = fmaf(va2a[it].w, fast_rcp(fmaf(eqa[it].w, u1.y, 1.f)), acc);
                        acc = fmaf(va2b[it].x, fast_rcp(fmaf(eqb[it].x, u2.x, 1.f)), acc);
                        acc = fmaf(va2b[it].y, fast_rcp(fmaf(eqb[it].y, u2.y, 1.f)), acc);
                        acc = fmaf(va2b[it].z, fast_rcp(fmaf(eqb[it].z, u3.x, 1.f)), acc);
                        acc = fmaf(va2b[it].w, fast_rcp(fmaf(eqb[it].w, u3.y, 1.f)), acc);
                    }
                    acc += __shfl_xor(acc, 1); acc += __shfl_xor(acc, 2);
                    acc += __shfl_xor(acc, 4); acc += __shfl_xor(acc, 8);
                    if (kl == 0) w_s[s] = __expf(acc);   // Va_b: softmax-invariant
                }
            }
            __syncthreads();

            // ---- denom (wave0) overlapped with unnormalized ctx accum from regs (all) ----
            if (tid < 64) {
                float sm = w_s[tid] + w_s[tid + 64];
                #pragma unroll
                for (int off = 32; off > 0; off >>= 1) sm += __shfl_down(sm, off);
                if (tid == 0) red[1] = fast_rcp(sm);
            }
            {
                const int dq = tid & 127, sg = tid >> 7;
                float4 a = {0.f, 0.f, 0.f, 0.f};
                #pragma unroll
                for (int si = 0; si < 32; ++si) {
                    const float wgt = w_s[sg * 32 + si];
                    const float2 e0 = unpackbf2(ereg[si].x), e1 = unpackbf2(ereg[si].y);
                    a.x = fmaf(wgt, e0.x, a.x);
                    a.y = fmaf(wgt, e0.y, a.y);
                    a.z = fmaf(wgt, e1.x, a.z);
                    a.w = fmaf(wgt, e1.y, a.w);
                }
                ((float4*)psq)[sg * 128 + dq] = a;
            }
            __syncthreads();
            if (tid < 128) {
                const float rn = red[1];
                const float4* p4 = (const float4*)psq;
                float4 a = p4[tid], b2 = p4[128 + tid], c2 = p4[256 + tid], d2 = p4[384 + tid];
                const float rx = (a.x + b2.x + c2.x + d2.x) * rn;
                const float ry = (a.y + b2.y + c2.y + d2.y) * rn;
                const float rz = (a.z + b2.z + c2.z + d2.z) * rn;
                const float rw = (a.w + b2.w + c2.w + d2.w) * rn;
                cstore64(CxS + bl * 128 + tid,
                         (u64)packbf2(rx, ry) | ((u64)packbf2(rz, rw) << 32));
            }
            __syncthreads();
            if (tid == 0) cstore32(FC + bl * 16, (u32)(t + 1));
            else if (tid >= 128 && tid < 256)   // ATT write off the FC critical path
                out[OFF_OUT_ATT + ((size_t)b * 64 + t) * 128 + (tid - 128)] = w_s[tid - 128] * red[1];
        }
    } else {
        // ========== GRU block: 16 dims, 16 b, MFMA tiles, weights in B-frag regs ==========
        // waves 0-2: gh | waves 3-5: FC-poll + ctx stage (ph1), gi MFMA (ph2)
        // wave 6: q = h@Wa slice (MFMA) -> tagged exp(2q) store (no drain/flag) | wave 7: coords
        const int idx = r - 16, d0 = idx * 16;
        u32*   hbu  = (u32*)smraw;                  // [16][260] bf16-pairs (padded)
        u32*   cbu  = (u32*)(smraw + 16640);        // [16][260] ctx staging
        float* gh_s = (float*)(smraw + 33280);      // 768
        float* gi_s = (float*)(smraw + 36352);      // 768
        float* x_s  = (float*)(smraw + 39424);      // 48
        float* wx_s = (float*)(smraw + 39616);      // 144
        float* wo_s = (float*)(smraw + 40192);      // 1536 + 3

        u64* QXW = (u64*)((char*)ws + OFF_QX + (size_t)g * 131072u);

        const int mn = lane & 15, quad = lane >> 4;

        // ---- B-fragments: wv 0-2 = gh gates R,Z,N; wv 3-5 = gi gates; wv 6 = Wa cols ----
        short8 bfrag[16];
        float qbias = 0.f;
        if (wv < 3) {
            const float* wrow = W_hh + (size_t)(wv * 512 + d0 + mn) * 512;
            #pragma unroll
            for (int kb = 0; kb < 16; ++kb) {
                const int k0 = kb * 32 + quad * 8;
                U8 tpk;
                #pragma unroll
                for (int c = 0; c < 4; ++c)
                    tpk.u[c] = packbf2(wrow[k0 + 2 * c], wrow[k0 + 2 * c + 1]);
                bfrag[kb] = tpk.s;
            }
        } else if (wv < 6) {
            const float* wrow = W_ih + (size_t)((wv - 3) * 512 + d0 + mn) * 515;
            #pragma unroll
            for (int kb = 0; kb < 16; ++kb) {
                const int k0 = kb * 32 + quad * 8;
                U8 tpk;
                #pragma unroll
                for (int c = 0; c < 4; ++c)
                    tpk.u[c] = packbf2(wrow[k0 + 2 * c], wrow[k0 + 2 * c + 1]);
                bfrag[kb] = tpk.s;
            }
        } else if (wv == 6) {
            // B[k][col=d0+mn] = Wa_w[k][d0+mn]
            #pragma unroll
            for (int kb = 0; kb < 16; ++kb) {
                const int k0 = kb * 32 + quad * 8;
                U8 tpk;
                #pragma unroll
                for (int c = 0; c < 4; ++c)
                    tpk.u[c] = packbf2(Wa_w[(size_t)(k0 + 2 * c) * 512 + d0 + mn],
                                       Wa_w[(size_t)(k0 + 2 * c + 1) * 512 + d0 + mn]);
                bfrag[kb] = tpk.s;
            }
            qbias = Wa_b[d0 + mn];
        }
        if (tid < 144) {
            const int dd = tid / 9, rem = tid - dd * 9, g3 = rem / 3, c = rem - g3 * 3;
            wx_s[tid] = W_ih[(size_t)(g3 * 512 + d0 + dd) * 515 + 512 + c];
        }
        for (int i = tid; i < 1536; i += 512) wo_s[i] = Wo_w[i];
        if (tid < 3) wo_s[1536 + tid] = Wo_b[tid];

        const int gb = tid >> 4, gd = tid & 15;     // gates mapping (tid<256)
        float hold = 0.f, bih[3], bhh[3];
        if (tid < 256) {
            hold = e_last[(size_t)(g * 16 + gb) * 512 + d0 + gd];
            #pragma unroll
            for (int g3 = 0; g3 < 3; ++g3) {
                bih[g3] = b_ih[g3 * 512 + d0 + gd];
                bhh[g3] = b_hh[g3 * 512 + d0 + gd];
            }
        }

        for (int t = 0; t < 64; ++t) {
            const int slot = t & 1;
            const u64* HxS = HX + slot * 2048;
            const u64* CxS = CX + slot * 2048;
            u64* HxW = HX + ((t + 1) & 1) * 2048;

            // dependency-aware h wait: wave w loads d4 in half (w&1) -> poll those 16 producers
            if (lane < 16) {
                const u32* f = FH + ((wv & 1) * 16 + lane) * 16;
                while (cload32(f) < (u32)t) {}
            }
            #pragma unroll
            for (int u = 0; u < 4; ++u) {
                const int i = tid + 512 * u;
                const u64 v = cload64(HxS + i);
                *(u64*)(hbu + (i >> 7) * 260 + (i & 127) * 2) = v;
            }
            __syncthreads();

            // ---- phase 1: gh (wv0-2) | FC poll + ctx stage (wv3-5) | q (wv6) | coords (wv7)
            if (wv < 3) {
                f32x4 c = {0.f, 0.f, 0.f, 0.f};
                #pragma unroll
                for (int kb = 0; kb < 16; ++kb) {
                    U8 a; a.q = *(const uint4*)(hbu + mn * 260 + kb * 16 + quad * 4);
                    c = __builtin_amdgcn_mfma_f32_16x16x32_bf16(a.s, bfrag[kb], c, 0, 0, 0);
                }
                #pragma unroll
                for (int reg = 0; reg < 4; ++reg)
                    gh_s[((quad * 4 + reg) * 16 + mn) * 3 + wv] = c[reg];
            } else if (wv < 6) {
                if (lane < 16) { const u32* f = FC + lane * 16; while (cload32(f) < (u32)(t + 1)) {} }
                const int thr = (wv - 3) * 64 + lane;
                for (int i = thr; i < 2048; i += 192) {
                    const u64 v = cload64(CxS + i);
                    *(u64*)(cbu + (i >> 7) * 260 + (i & 127) * 2) = v;
                }
            } else if (wv == 6) {
                f32x4 c = {0.f, 0.f, 0.f, 0.f};
                #pragma unroll
                for (int kb = 0; kb < 16; ++kb) {
                    U8 a; a.q = *(const uint4*)(hbu + mn * 260 + kb * 16 + quad * 4);
                    c = __builtin_amdgcn_mfma_f32_16x16x32_bf16(a.s, bfrag[kb], c, 0, 0, 0);
                }
                // tagged EQ publish: {tag | exp(2*(q+bias))} per col, no drain, no flag
                u64* QxW = QXW + slot * 8192;
                const u64 tg64 = (u64)(u32)(t + 1) << 32;
                #pragma unroll
                for (int reg = 0; reg < 4; ++reg) {
                    const float q0 = c[reg] + qbias;
                    const float e  = __expf(2.f * q0);
                    cstore64(QxW + (size_t)(quad * 4 + reg) * 512 + d0 + mn,
                             tg64 | (u64)__float_as_uint(e));
                }
            } else {
                const int tt = tid - 448, cb = tt >> 2, kl = tt & 3;
                if (t > 0) {
                    float a0 = 0.f, a1 = 0.f, a2 = 0.f;
                    #pragma unroll 4
                    for (int c = 0; c < 64; ++c) {
                        const int p = kl * 64 + c;
                        const float2 hv = unpackbf2(hbu[cb * 260 + p]);
                        const float* w0 = wo_s + 2 * p * 3;
                        a0 = fmaf(hv.x, w0[0], fmaf(hv.y, w0[3], a0));
                        a1 = fmaf(hv.x, w0[1], fmaf(hv.y, w0[4], a1));
                        a2 = fmaf(hv.x, w0[2], fmaf(hv.y, w0[5], a2));
                    }
                    a0 += __shfl_xor(a0, 1); a1 += __shfl_xor(a1, 1); a2 += __shfl_xor(a2, 1);
                    a0 += __shfl_xor(a0, 2); a1 += __shfl_xor(a1, 2); a2 += __shfl_xor(a2, 2);
                    if (kl == 0) {
                        x_s[cb * 3 + 0] = a0 + wo_s[1536];
                        x_s[cb * 3 + 1] = a1 + wo_s[1537];
                        x_s[cb * 3 + 2] = a2 + wo_s[1538];
                    }
                } else if (tt < 48) x_s[tt] = 0.f;
            }
            __syncthreads();

            // ---- phase 2: gi MFMA (wv3-5) | coords out write (idx 0) ----
            if (wv >= 3 && wv < 6) {
                f32x4 c = {0.f, 0.f, 0.f, 0.f};
                #pragma unroll
                for (int kb = 0; kb < 16; ++kb) {
                    U8 a; a.q = *(const uint4*)(cbu + mn * 260 + kb * 16 + quad * 4);
                    c = __builtin_amdgcn_mfma_f32_16x16x32_bf16(a.s, bfrag[kb], c, 0, 0, 0);
                }
                #pragma unroll
                for (int reg = 0; reg < 4; ++reg)
                    gi_s[((quad * 4 + reg) * 16 + mn) * 3 + (wv - 3)] = c[reg];
            } else if (idx == 0 && t > 0 && tid < 48) {
                out[((size_t)(g * 16 + tid / 3) * 64 + (t - 1)) * 3 + tid % 3] = x_s[tid];
            }
            __syncthreads();

            // ---- gates + h update ----
            if (tid < 256) {
                const int ob = (gb * 16 + gd) * 3;
                const float x0 = x_s[gb * 3 + 0], x1 = x_s[gb * 3 + 1], x2 = x_s[gb * 3 + 2];
                const float giR = gi_s[ob + 0] + bih[0]
                                + x0 * wx_s[gd * 9 + 0] + x1 * wx_s[gd * 9 + 1] + x2 * wx_s[gd * 9 + 2];
                const float giZ = gi_s[ob + 1] + bih[1]
                                + x0 * wx_s[gd * 9 + 3] + x1 * wx_s[gd * 9 + 4] + x2 * wx_s[gd * 9 + 5];
                const float giN = gi_s[ob + 2] + bih[2]
                                + x0 * wx_s[gd * 9 + 6] + x1 * wx_s[gd * 9 + 7] + x2 * wx_s[gd * 9 + 8];
                const float ghR = gh_s[ob + 0] + bhh[0];
                const float ghZ = gh_s[ob + 1] + bhh[1];
                const float ghN = gh_s[ob + 2] + bhh[2];
                const float rg = sigm_f(giR + ghR);
                const float zg = sigm_f(giZ + ghZ);
                const float ng = tanh5(giN + rg * ghN);
                const float hnew = (1.f - zg) * ng + zg * hold;
                hold = hnew;
                const float s1 = __shfl_down(hnew, 1);
                const float s2 = __shfl_down(hnew, 2);
                const float s3 = __shfl_down(hnew, 3);
                if ((gd & 3) == 0)
                    cstore64(HxW + gb * 128 + ((d0 + gd) >> 2),
                             (u64)packbf2(hnew, s1) | ((u64)packbf2(s2, s3) << 32));
                if (t == 63)
                    out[OFF_OUT_HT + (size_t)(g * 16 + gb) * 512 + d0 + gd] = hnew;
            }
            __syncthreads();
            if (tid == 0) cstore32(FH + idx * 16, (u32)(t + 1));
        }

        // ---- final: coords(h_64) -> out[:,63] ----
        if (tid < 32) { const u32* f = FH + tid * 16; while (cload32(f) < 64u) {} }
        __syncthreads();
        #pragma unroll
        for (int u = 0; u < 4; ++u) {
            const int i = tid + 512 * u;
            const u64 v = cload64(HX + i);   // slot 0 holds h_64
            *(u64*)(hbu + (i >> 7) * 260 + (i & 127) * 2) = v;
        }
        __syncthreads();
        if (wv >= 6) {
            const int tt = tid - 384, cb = tt >> 3, kl = tt & 7;
            float a0 = 0.f, a1 = 0.f, a2 = 0.f;
            #pragma unroll 4
            for (int c = 0; c < 32; ++c) {
                const int p = kl * 32 + c;
                const float2 hv = unpackbf2(hbu[cb * 260 + p]);
                const float* w0 = wo_s + 2 * p * 3;
                a0 = fmaf(hv.x, w0[0], fmaf(hv.y, w0[3], a0));
                a1 = fmaf(hv.x, w0[1], fmaf(hv.y, w0[4], a1));
                a2 = fmaf(hv.x, w0[2], fmaf(hv.y, w0[5], a2));
            }
            a0 += __shfl_xor(a0, 1); a1 += __shfl_xor(a1, 1); a2 += __shfl_xor(a2, 1);
            a0 += __shfl_xor(a0, 2); a1 += __shfl_xor(a1, 2); a2 += __shfl_xor(a2, 2);
            a0 += __shfl_xor(a0, 4); a1 += __shfl_xor(a1, 4); a2 += __shfl_xor(a2, 4);
            if (kl == 0) {
                x_s[cb * 3 + 0] = a0 + wo_s[1536];
                x_s[cb * 3 + 1] = a1 + wo_s[1537];
                x_s[cb * 3 + 2] = a2 + wo_s[1538];
            }
        }
        __syncthreads();
        if (idx == 0 && tid < 48)
            out[((size_t)(g * 16 + tid / 3) * 64 + 63) * 3 + tid % 3] = x_s[tid];
    }
}

extern "C" void kernel_launch(void* const* d_in, const int* in_sizes, int n_in,
                              void* d_out, int out_size, void* d_ws, size_t ws_size,
                              hipStream_t stream) {
    const float* e_all  = (const float*)d_in[0];
    const float* e_last = (const float*)d_in[1];
    const float* Wa_w   = (const float*)d_in[2];
    const float* Wa_b   = (const float*)d_in[3];
    const float* Ua_w   = (const float*)d_in[4];
    const float* Ua_b   = (const float*)d_in[5];
    const float* Va_w   = (const float*)d_in[6];
    const float* W_ih   = (const float*)d_in[8];
    const float* W_hh   = (const float*)d_in[9];
    const float* b_ih   = (const float*)d_in[10];
    const float* b_hh   = (const float*)d_in[11];
    const float* Wo_w   = (const float*)d_in[12];
    const float* Wo_b   = (const float*)d_in[13];
    float* outp = (float*)d_out;
    float* ws   = (float*)d_ws;

    hipFuncSetAttribute((const void*)prep_kernel,
                        hipFuncAttributeMaxDynamicSharedMemorySize, PREP_LDS);
    hipFuncSetAttribute((const void*)decode_kernel,
                        hipFuncAttributeMaxDynamicSharedMemorySize, DYN_LDS);

    hipLaunchKernelGGL(prep_kernel, dim3(1024), dim3(256), PREP_LDS, stream,
                       e_all, e_last, Ua_w, Ua_b, ws);

    void* args[] = { (void*)&e_all, (void*)&e_last, (void*)&Wa_w, (void*)&Wa_b,
                     (void*)&Va_w,
                     (void*)&W_ih, (void*)&W_hh, (void*)&b_ih, (void*)&b_hh,
                     (void*)&Wo_w, (void*)&Wo_b, (void*)&outp, (void*)&ws };
    hipError_t err = hipLaunchCooperativeKernel((void*)decode_kernel, dim3(NBLK), dim3(NTHR),
                                                args, DYN_LDS, stream);
    if (err != hipSuccess) {
        // fallback: 192 blocks x 142KB LDS -> 1 block/CU, co-resident on 256 CUs
        hipLaunchKernelGGL(decode_kernel, dim3(NBLK), dim3(NTHR), DYN_LDS, stream,
                           e_all, e_last, Wa_w, Wa_b, Va_w,
                           W_ih, W_hh, b_ih, b_hh, Wo_w, Wo_b, outp, ws);
    }
}

// Round 12
// 839.130 us; speedup vs baseline: 1.3310x; 1.0894x over previous
//
#include <hip/hip_runtime.h>

typedef unsigned int u32;
typedef unsigned long long u64;
typedef float f32x4 __attribute__((ext_vector_type(4)));
typedef short short8 __attribute__((ext_vector_type(8)));

// B=64, S=128, D=512, T=64. 4 groups x 16 batches.
// ws byte offsets:
#define OFF_UKB 0u          // u32[64*128*256] bf16 Uk
#define OFF_QX  16777216u   // u64[4 groups][2 slots][16 b][512] tagged f32 EQ (131072 B/group)
#define OFF_EX  17563648u   // per-group exchange
#define G_BYTES 102400u
// group layout: HX u64[2][2048] @0 | CX u64[2][4096] @32768 (tagged {t|2bf16}) | FH u32 @98304 (32x64B)

#define OFF_OUT_HT  12288u
#define OFF_OUT_ATT 45056u

#define NBLK 192
#define NTHR 512
#define DYN_LDS 145408
#define PREP_LDS 36864

__device__ __forceinline__ float fast_rcp(float x) { return __builtin_amdgcn_rcpf(x); }
// tanh = 1 - 2/(e^{2x}+1): graceful at +/-inf (rcp(inf)=0), no clamps needed
__device__ __forceinline__ float tanh5(float x) {
    float e = __expf(2.f * x);
    return 1.f - 2.f * fast_rcp(e + 1.f);
}
__device__ __forceinline__ float sigm_f(float x) { return fast_rcp(1.f + __expf(-x)); }

__device__ __forceinline__ u32 packbf2(float a, float b) {
    u32 ua = __float_as_uint(a); ua += 0x7FFFu + ((ua >> 16) & 1u);
    u32 ub = __float_as_uint(b); ub += 0x7FFFu + ((ub >> 16) & 1u);
    return (ua >> 16) | (ub & 0xFFFF0000u);
}
__device__ __forceinline__ float2 unpackbf2(u32 u) {
    return make_float2(__uint_as_float(u << 16), __uint_as_float(u & 0xFFFF0000u));
}
// split x into bf16-exact hi + residual lo (lo gets bf16-rounded later)
__device__ __forceinline__ float bf16hi(float x, float& lo) {
    u32 u = __float_as_uint(x); u += 0x7FFFu + ((u >> 16) & 1u); u &= 0xFFFF0000u;
    const float h = __uint_as_float(u); lo = x - h; return h;
}

// relaxed agent-scope accessors: per-access cache bypass, no cache-wide inv/wb
__device__ __forceinline__ u64 cload64(const u64* p) {
    return __hip_atomic_load(p, __ATOMIC_RELAXED, __HIP_MEMORY_SCOPE_AGENT);
}
__device__ __forceinline__ void cstore64(u64* p, u64 v) {
    __hip_atomic_store(p, v, __ATOMIC_RELAXED, __HIP_MEMORY_SCOPE_AGENT);
}
__device__ __forceinline__ u32 cload32(const u32* p) {
    return __hip_atomic_load(p, __ATOMIC_RELAXED, __HIP_MEMORY_SCOPE_AGENT);
}
__device__ __forceinline__ void cstore32(u32* p, u32 v) {
    __hip_atomic_store(p, v, __ATOMIC_RELAXED, __HIP_MEMORY_SCOPE_AGENT);
}

union U8 { u32 u[4]; uint4 q; short8 s; };

// ---------------- prep: Uk GEMM (MFMA, hi/lo bf16 split) + H0 + flag/CX/QX reset ----------------
// grid 1024 x 256. GEMM tile: 64 rows x 64 cols, K=512 in 8 stages of 64 (36KB LDS -> 4 blk/CU).
__global__ __launch_bounds__(256) void prep_kernel(
    const float* __restrict__ e_all, const float* __restrict__ e_last,
    const float* __restrict__ Ua_w,  const float* __restrict__ Ua_b,
    float* __restrict__ ws)
{
    extern __shared__ char pls[];
    u32* Ahi = (u32*)pls;            // [64 rows][36 kp]
    u32* Alo = Ahi + 64 * 36;
    u32* Bhi = Alo + 64 * 36;        // [64 cols][36 kp]
    u32* Blo = Bhi + 64 * 36;

    u32* UKB = (u32*)((char*)ws + OFF_UKB);

    const int blk = blockIdx.x, tid = threadIdx.x;
    const int gtid = blk * 256 + tid, gstride = 1024 * 256;

    // FH zero: 4 groups x 512 u32
    for (int i = gtid; i < 2048; i += gstride) {
        const int g = i >> 9, j = i & 511;
        ((u32*)((char*)ws + OFF_EX + (size_t)g * G_BYTES + 98304))[j] = 0u;
    }
    // CX zero (tagged words; tag 0 != any step tag; kills cross-run leftovers)
    for (int i = gtid; i < 32768; i += gstride) {
        const int g = i >> 13, j = i & 8191;
        ((u64*)((char*)ws + OFF_EX + (size_t)g * G_BYTES + 32768))[j] = 0ull;
    }
    // QX zero
    for (int i = gtid; i < 65536; i += gstride)
        ((u64*)((char*)ws + OFF_QX))[i] = 0ull;
    // H0 -> HX slot 0 (u64 = 4 bf16)
    for (int i = gtid; i < 8192; i += gstride) {
        const int g = i >> 11, i2 = i & 2047;
        const float* ep = e_last + ((size_t)(g * 16 + (i2 >> 7)) * 512) + 4 * (i2 & 127);
        u64* HX = (u64*)((char*)ws + OFF_EX + (size_t)g * G_BYTES);
        HX[i2] = (u64)packbf2(ep[0], ep[1]) | ((u64)packbf2(ep[2], ep[3]) << 32);
    }

    // ---- Uk = e_all[8192x512] @ Ua[512x512] + b, MFMA with hi+lo compensation ----
    const int r0 = (blk >> 3) * 64, c0 = (blk & 7) * 64;
    const int lane = tid & 63, wv = tid >> 6;
    const int mn = lane & 15, quad = lane >> 4;

    f32x4 acc[4];
    #pragma unroll
    for (int rg = 0; rg < 4; ++rg) acc[rg] = (f32x4){0.f, 0.f, 0.f, 0.f};

    for (int ks = 0; ks < 8; ++ks) {
        if (ks) __syncthreads();   // protect LDS reuse across stages
        // stage A: 64 rows x 16 float4 (k = ks*64 .. +63)
        for (int i = tid; i < 1024; i += 256) {
            const int row = i >> 4, q4i = i & 15;
            const float4 e = *(const float4*)(e_all + (size_t)(r0 + row) * 512 + ks * 64 + 4 * q4i);
            float l0, l1, l2, l3;
            const float h0 = bf16hi(e.x, l0), h1 = bf16hi(e.y, l1);
            const float h2 = bf16hi(e.z, l2), h3 = bf16hi(e.w, l3);
            Ahi[row * 36 + 2 * q4i]     = packbf2(h0, h1);
            Ahi[row * 36 + 2 * q4i + 1] = packbf2(h2, h3);
            Alo[row * 36 + 2 * q4i]     = packbf2(l0, l1);
            Alo[row * 36 + 2 * q4i + 1] = packbf2(l2, l3);
        }
        // stage B: 32 kp x 64 cols
        for (int i = tid; i < 2048; i += 256) {
            const int col = i & 63, kp = i >> 6;
            const float b0 = Ua_w[(size_t)(ks * 64 + 2 * kp) * 512 + c0 + col];
            const float b1 = Ua_w[(size_t)(ks * 64 + 2 * kp + 1) * 512 + c0 + col];
            float l0, l1;
            const float h0 = bf16hi(b0, l0), h1 = bf16hi(b1, l1);
            Bhi[col * 36 + kp] = packbf2(h0, h1);
            Blo[col * 36 + kp] = packbf2(l0, l1);
        }
        __syncthreads();
        #pragma unroll
        for (int kb = 0; kb < 2; ++kb) {
            const int fo = kb * 16 + quad * 4;
            U8 bh, bl;
            bh.q = *(const uint4*)(Bhi + (wv * 16 + mn) * 36 + fo);
            bl.q = *(const uint4*)(Blo + (wv * 16 + mn) * 36 + fo);
            #pragma unroll
            for (int rg = 0; rg < 4; ++rg) {
                U8 ah, al;
                ah.q = *(const uint4*)(Ahi + (rg * 16 + mn) * 36 + fo);
                al.q = *(const uint4*)(Alo + (rg * 16 + mn) * 36 + fo);
                acc[rg] = __builtin_amdgcn_mfma_f32_16x16x32_bf16(al.s, bh.s, acc[rg], 0, 0, 0);
                acc[rg] = __builtin_amdgcn_mfma_f32_16x16x32_bf16(ah.s, bl.s, acc[rg], 0, 0, 0);
                acc[rg] = __builtin_amdgcn_mfma_f32_16x16x32_bf16(ah.s, bh.s, acc[rg], 0, 0, 0);
            }
        }
    }
    // epilogue: bias + pack pairs (cols mn,mn+1 via shfl) + store
    const int col = c0 + wv * 16 + mn;
    const float bias = Ua_b[col];
    #pragma unroll
    for (int rg = 0; rg < 4; ++rg) {
        #pragma unroll
        for (int reg = 0; reg < 4; ++reg) {
            const float v = acc[rg][reg] + bias;
            const float v1 = __shfl_down(v, 1);
            if (!(mn & 1))
                UKB[(size_t)(r0 + rg * 16 + quad * 4 + reg) * 256 + (col >> 1)] = packbf2(v, v1);
        }
    }
}

// ---------------- persistent decode: per group 16 attn + 32 GRU blocks ----------------
__global__ __launch_bounds__(512, 1) void decode_kernel(
    const float* __restrict__ e_all,
    const float* __restrict__ e_last,
    const float* __restrict__ Wa_w,  const float* __restrict__ Wa_b,
    const float* __restrict__ Va_w,
    const float* __restrict__ W_ih,  const float* __restrict__ W_hh,
    const float* __restrict__ b_ih,  const float* __restrict__ b_hh,
    const float* __restrict__ Wo_w,  const float* __restrict__ Wo_b,
    float* __restrict__ out, float* __restrict__ ws)
{
    extern __shared__ char smraw[];

    const u32* UKB = (const u32*)((char*)ws + OFF_UKB);

    const int tid = threadIdx.x;
    const int bi  = blockIdx.x;
    const int g   = bi / 48, r = bi % 48;
    const int lane = tid & 63, wv = tid >> 6;

    char* gbase = (char*)ws + OFF_EX + (size_t)g * G_BYTES;
    u64* HX = (u64*)gbase;
    u64* CX = (u64*)(gbase + 32768);   // [2 slots][4096] tagged
    u32* FH = (u32*)(gbase + 98304);

    if (r < 16) {
        // ===================== attention block: one per b =====================
        // EU = exp(2*Uk) in LDS; EQ arrives tagged; ctx leaves tagged (no drain, no flag).
        // tanh(q+Uk) = 1 - 2*rcp(EQ*EU + 1); score = vaSum + sum (-2Va)*rcp(...). No max-sub.
        const int bl = r, b = g * 16 + bl;
        u32*   EuL  = (u32*)smraw;                 // 131072 B: exp(2*Uk[b]) bf16 [128 s][256 pairs]
        float* eq_s = (float*)(smraw + 131072);    // 512 f32: exp(2*q)
        float* w_s  = (float*)(smraw + 133120);    // 128 (raw exp)
        float* red  = (float*)(smraw + 133632);    // 16
        float* psq  = (float*)(smraw + 133696);    // 8192 B: ctx partials

        const u64* QXR = (const u64*)((char*)ws + OFF_QX + (size_t)g * 131072u);

        // stage EU = exp(2*Uk[b]) into LDS once (persistent across all 64 steps)
        {
            const uint4* src = (const uint4*)(UKB + (size_t)b * 32768);
            uint4* dst = (uint4*)EuL;
            #pragma unroll
            for (int i = 0; i < 16; ++i) {
                uint4 u = src[tid + 512 * i];
                float2 p;
                p = unpackbf2(u.x); u.x = packbf2(__expf(2.f * p.x), __expf(2.f * p.y));
                p = unpackbf2(u.y); u.y = packbf2(__expf(2.f * p.x), __expf(2.f * p.y));
                p = unpackbf2(u.z); u.z = packbf2(__expf(2.f * p.x), __expf(2.f * p.y));
                p = unpackbf2(u.w); u.w = packbf2(__expf(2.f * p.x), __expf(2.f * p.y));
                dst[tid + 512 * i] = u;
            }
        }
        // E[b] slice into registers once (bf16-packed from f32 e_all)
        uint2 ereg[32];
        {
            const int dq = tid & 127, sg = tid >> 7;
            const float* ep = e_all + (size_t)b * 65536;
            #pragma unroll
            for (int si = 0; si < 32; ++si) {
                const float4 e = *(const float4*)(ep + (size_t)(sg * 32 + si) * 512 + 4 * dq);
                ereg[si] = make_uint2(packbf2(e.x, e.y), packbf2(e.z, e.w));
            }
        }
        // Va-derived constants: va2 = -2*Va slices, vaSum = sum over my 32 dims
        const int kl = lane & 15;
        float4 va2a[4], va2b[4];
        float vaSum = 0.f;
        #pragma unroll
        for (int it = 0; it < 4; ++it) {
            const float4 a  = *(const float4*)(Va_w + (it * 16 + kl) * 8);
            const float4 b2 = *(const float4*)(Va_w + (it * 16 + kl) * 8 + 4);
            vaSum += a.x + a.y + a.z + a.w + b2.x + b2.y + b2.z + b2.w;
            va2a[it] = make_float4(-2.f * a.x,  -2.f * a.y,  -2.f * a.z,  -2.f * a.w);
            va2b[it] = make_float4(-2.f * b2.x, -2.f * b2.y, -2.f * b2.z, -2.f * b2.w);
        }
        __syncthreads();

        for (int t = 0; t < 64; ++t) {
            const int slot = t & 1;
            const u32 tg = (u32)(t + 1);
            u64* CxS = CX + slot * 4096;
            const u64* QxS = QXR + slot * 8192 + (size_t)bl * 512;

            // tagged EQ: each of tid<256 spins on its own 2 words (data IS the signal)
            if (tid < 256) {
                u64 v0 = cload64(QxS + 2 * tid), v1 = cload64(QxS + 2 * tid + 1);
                while ((u32)(v0 >> 32) != tg) v0 = cload64(QxS + 2 * tid);
                while ((u32)(v1 >> 32) != tg) v1 = cload64(QxS + 2 * tid + 1);
                ((float2*)eq_s)[tid] = make_float2(__uint_as_float((u32)v0),
                                                   __uint_as_float((u32)v1));
            }
            __syncthreads();

            // ---- scores: vaSum + sum va2*rcp(EQ*EU+1), then exp ----
            {
                float4 eqa[4], eqb[4];
                const float4* q4 = (const float4*)eq_s;
                #pragma unroll
                for (int it = 0; it < 4; ++it) {
                    eqa[it] = q4[(it * 16 + kl) * 2];  eqb[it] = q4[(it * 16 + kl) * 2 + 1];
                }
                const int sbase = wv * 16 + (lane >> 4);
                #pragma unroll
                for (int sg = 0; sg < 4; ++sg) {
                    const int s = sbase + sg * 4;
                    const uint4* uk4 = (const uint4*)EuL + (size_t)s * 64;
                    float acc = vaSum;
                    #pragma unroll
                    for (int it = 0; it < 4; ++it) {
                        const uint4 u = uk4[it * 16 + kl];
                        const float2 u0 = unpackbf2(u.x), u1 = unpackbf2(u.y);
                        const float2 u2 = unpackbf2(u.z), u3 = unpackbf2(u.w);
                        acc = fmaf(va2a[it].x, fast_rcp(fmaf(eqa[it].x, u0.x, 1.f)), acc);
                        acc = fmaf(va2a[it].y, fast_rcp(fmaf(eqa[it].y, u0.y, 1.f)), acc);
                        acc = fmaf(va2a[it].z, fast_rcp(fmaf(eqa[it].z, u1.x, 1.f)), acc);
                        acc = fmaf(va2a[it].w, fast_rcp(fmaf(eqa[it].w, u1.y, 1.f)), acc);
                        acc = fmaf(va2b[it].x, fast_rcp(fmaf(eqb[it].x, u2.x, 1.f)), acc);
                        acc = fmaf(va2b[it].y, fast_rcp(fmaf(eqb[it].y, u2.y, 1.f)), acc);
                        acc = fmaf(va2b[it].z, fast_rcp(fmaf(eqb[it].z, u3.x, 1.f)), acc);
                        acc = fmaf(va2b[it].w, fast_rcp(fmaf(eqb[it].w, u3.y, 1.f)), acc);
                    }
                    acc += __shfl_xor(acc, 1); acc += __shfl_xor(acc, 2);
                    acc += __shfl_xor(acc, 4); acc += __shfl_xor(acc, 8);
                    if (kl == 0) w_s[s] = __expf(acc);   // Va_b: softmax-invariant
                }
            }
            __syncthreads();

            // ---- denom (wave0) overlapped with unnormalized ctx accum from regs (all) ----
            if (tid < 64) {
                float sm = w_s[tid] + w_s[tid + 64];
                #pragma unroll
                for (int off = 32; off > 0; off >>= 1) sm += __shfl_down(sm, off);
                if (tid == 0) red[1] = fast_rcp(sm);
            }
            {
                const int dq = tid & 127, sg = tid >> 7;
                float4 a = {0.f, 0.f, 0.f, 0.f};
                #pragma unroll
                for (int si = 0; si < 32; ++si) {
                    const float wgt = w_s[sg * 32 + si];
                    const float2 e0 = unpackbf2(ereg[si].x), e1 = unpackbf2(ereg[si].y);
                    a.x = fmaf(wgt, e0.x, a.x);
                    a.y = fmaf(wgt, e0.y, a.y);
                    a.z = fmaf(wgt, e1.x, a.z);
                    a.w = fmaf(wgt, e1.y, a.w);
                }
                ((float4*)psq)[sg * 128 + dq] = a;
            }
            __syncthreads();
            if (tid < 128) {
                const float rn = red[1];
                const float4* p4 = (const float4*)psq;
                float4 a = p4[tid], b2 = p4[128 + tid], c2 = p4[256 + tid], d2 = p4[384 + tid];
                const float rx = (a.x + b2.x + c2.x + d2.x) * rn;
                const float ry = (a.y + b2.y + c2.y + d2.y) * rn;
                const float rz = (a.z + b2.z + c2.z + d2.z) * rn;
                const float rw = (a.w + b2.w + c2.w + d2.w) * rn;
                const u64 tg64 = (u64)tg << 32;
                cstore64(CxS + (size_t)bl * 256 + 2 * tid,     tg64 | (u64)packbf2(rx, ry));
                cstore64(CxS + (size_t)bl * 256 + 2 * tid + 1, tg64 | (u64)packbf2(rz, rw));
            } else if (tid < 256) {   // ATT write, same phase (red/w_s ready; barrier-free tail)
                out[OFF_OUT_ATT + ((size_t)b * 64 + t) * 128 + (tid - 128)] = w_s[tid - 128] * red[1];
            }
            // no trailing barrier: next-iter EQ barrier orders w_s/red/psq reuse
        }
    } else {
        // ========== GRU block: 16 dims, 16 b, MFMA tiles, weights in B-frag regs ==========
        // waves 0-2: gh | waves 3-6: tagged ctx round-spin stage (wv6 first q+EQ) | wave 7: coords
        const int idx = r - 16, d0 = idx * 16;
        u32*   hbu  = (u32*)smraw;                  // [16][260] bf16-pairs (padded)
        u32*   cbu  = (u32*)(smraw + 16640);        // [16][260] ctx staging
        float* gh_s = (float*)(smraw + 33280);      // 768
        float* gi_s = (float*)(smraw + 36352);      // 768
        float* x_s  = (float*)(smraw + 39424);      // 48
        float* wx_s = (float*)(smraw + 39616);      // 144
        float* wo_s = (float*)(smraw + 40192);      // 1536 + 3

        u64* QXW = (u64*)((char*)ws + OFF_QX + (size_t)g * 131072u);

        const int mn = lane & 15, quad = lane >> 4;

        // ---- B-fragments: wv 0-2 = gh gates R,Z,N; wv 3-5 = gi gates; wv 6 = Wa cols ----
        short8 bfrag[16];
        float qbias = 0.f;
        if (wv < 3) {
            const float* wrow = W_hh + (size_t)(wv * 512 + d0 + mn) * 512;
            #pragma unroll
            for (int kb = 0; kb < 16; ++kb) {
                const int k0 = kb * 32 + quad * 8;
                U8 tpk;
                #pragma unroll
                for (int c = 0; c < 4; ++c)
                    tpk.u[c] = packbf2(wrow[k0 + 2 * c], wrow[k0 + 2 * c + 1]);
                bfrag[kb] = tpk.s;
            }
        } else if (wv < 6) {
            const float* wrow = W_ih + (size_t)((wv - 3) * 512 + d0 + mn) * 515;
            #pragma unroll
            for (int kb = 0; kb < 16; ++kb) {
                const int k0 = kb * 32 + quad * 8;
                U8 tpk;
                #pragma unroll
                for (int c = 0; c < 4; ++c)
                    tpk.u[c] = packbf2(wrow[k0 + 2 * c], wrow[k0 + 2 * c + 1]);
                bfrag[kb] = tpk.s;
            }
        } else if (wv == 6) {
            // B[k][col=d0+mn] = Wa_w[k][d0+mn]
            #pragma unroll
            for (int kb = 0; kb < 16; ++kb) {
                const int k0 = kb * 32 + quad * 8;
                U8 tpk;
                #pragma unroll
                for (int c = 0; c < 4; ++c)
                    tpk.u[c] = packbf2(Wa_w[(size_t)(k0 + 2 * c) * 512 + d0 + mn],
                                       Wa_w[(size_t)(k0 + 2 * c + 1) * 512 + d0 + mn]);
                bfrag[kb] = tpk.s;
            }
            qbias = Wa_b[d0 + mn];
        }
        if (tid < 144) {
            const int dd = tid / 9, rem = tid - dd * 9, g3 = rem / 3, c = rem - g3 * 3;
            wx_s[tid] = W_ih[(size_t)(g3 * 512 + d0 + dd) * 515 + 512 + c];
        }
        for (int i = tid; i < 1536; i += 512) wo_s[i] = Wo_w[i];
        if (tid < 3) wo_s[1536 + tid] = Wo_b[tid];

        const int gb = tid >> 4, gd = tid & 15;     // gates mapping (tid<256)
        float hold = 0.f, bih[3], bhh[3];
        if (tid < 256) {
            hold = e_last[(size_t)(g * 16 + gb) * 512 + d0 + gd];
            #pragma unroll
            for (int g3 = 0; g3 < 3; ++g3) {
                bih[g3] = b_ih[g3 * 512 + d0 + gd];
                bhh[g3] = b_hh[g3 * 512 + d0 + gd];
            }
        }

        for (int t = 0; t < 64; ++t) {
            const int slot = t & 1;
            const u32 tg = (u32)(t + 1);
            const u64* HxS = HX + slot * 2048;
            const u64* CxS = CX + slot * 4096;
            u64* HxW = HX + ((t + 1) & 1) * 2048;

            // dependency-aware h wait: wave w loads d4 in half (w&1) -> poll those 16 producers
            if (lane < 16) {
                const u32* f = FH + ((wv & 1) * 16 + lane) * 16;
                while (cload32(f) < (u32)t) {}
            }
            #pragma unroll
            for (int u = 0; u < 4; ++u) {
                const int i = tid + 512 * u;
                const u64 v = cload64(HxS + i);
                *(u64*)(hbu + (i >> 7) * 260 + (i & 127) * 2) = v;
            }
            __syncthreads();

            // ---- phase 1: gh (wv0-2) | ctx round-spin (wv3-6; wv6 q+EQ first) | coords (wv7)
            if (wv < 3) {
                f32x4 c = {0.f, 0.f, 0.f, 0.f};
                #pragma unroll
                for (int kb = 0; kb < 16; ++kb) {
                    U8 a; a.q = *(const uint4*)(hbu + mn * 260 + kb * 16 + quad * 4);
                    c = __builtin_amdgcn_mfma_f32_16x16x32_bf16(a.s, bfrag[kb], c, 0, 0, 0);
                }
                #pragma unroll
                for (int reg = 0; reg < 4; ++reg)
                    gh_s[((quad * 4 + reg) * 16 + mn) * 3 + wv] = c[reg];
            } else if (wv == 7) {
                const int tt = tid - 448, cb = tt >> 2, kl = tt & 3;
                if (t > 0) {
                    float a0 = 0.f, a1 = 0.f, a2 = 0.f;
                    #pragma unroll 4
                    for (int c = 0; c < 64; ++c) {
                        const int p = kl * 64 + c;
                        const float2 hv = unpackbf2(hbu[cb * 260 + p]);
                        const float* w0 = wo_s + 2 * p * 3;
                        a0 = fmaf(hv.x, w0[0], fmaf(hv.y, w0[3], a0));
                        a1 = fmaf(hv.x, w0[1], fmaf(hv.y, w0[4], a1));
                        a2 = fmaf(hv.x, w0[2], fmaf(hv.y, w0[5], a2));
                    }
                    a0 += __shfl_xor(a0, 1); a1 += __shfl_xor(a1, 1); a2 += __shfl_xor(a2, 1);
                    a0 += __shfl_xor(a0, 2); a1 += __shfl_xor(a1, 2); a2 += __shfl_xor(a2, 2);
                    if (kl == 0) {
                        x_s[cb * 3 + 0] = a0 + wo_s[1536];
                        x_s[cb * 3 + 1] = a1 + wo_s[1537];
                        x_s[cb * 3 + 2] = a2 + wo_s[1538];
                    }
                } else if (tt < 48) x_s[tt] = 0.f;
            } else {
                // waves 3-6: wv6 publishes tagged EQ first, then all join ctx staging
                if (wv == 6) {
                    f32x4 c = {0.f, 0.f, 0.f, 0.f};
                    #pragma unroll
                    for (int kb = 0; kb < 16; ++kb) {
                        U8 a; a.q = *(const uint4*)(hbu + mn * 260 + kb * 16 + quad * 4);
                        c = __builtin_amdgcn_mfma_f32_16x16x32_bf16(a.s, bfrag[kb], c, 0, 0, 0);
                    }
                    u64* QxW = QXW + slot * 8192;
                    const u64 tg64 = (u64)tg << 32;
                    #pragma unroll
                    for (int reg = 0; reg < 4; ++reg) {
                        const float q0 = c[reg] + qbias;
                        const float e  = __expf(2.f * q0);
                        cstore64(QxW + (size_t)(quad * 4 + reg) * 512 + d0 + mn,
                                 tg64 | (u64)__float_as_uint(e));
                    }
                }
                // tagged ctx stage: thread thr spins col=thr across b=0..15, round-based
                const int thr = (wv - 3) * 64 + lane;   // 0..255
                u64 cc[16];
                u32 pend = 0xFFFFu;
                #pragma unroll
                for (int k = 0; k < 16; ++k) cc[k] = cload64(CxS + thr + 256 * k);
                #pragma unroll
                for (int k = 0; k < 16; ++k)
                    if ((u32)(cc[k] >> 32) == tg) { cbu[k * 260 + thr] = (u32)cc[k]; pend &= ~(1u << k); }
                while (pend) {
                    #pragma unroll
                    for (int k = 0; k < 16; ++k)
                        if (pend & (1u << k)) cc[k] = cload64(CxS + thr + 256 * k);
                    #pragma unroll
                    for (int k = 0; k < 16; ++k)
                        if ((pend & (1u << k)) && (u32)(cc[k] >> 32) == tg) {
                            cbu[k * 260 + thr] = (u32)cc[k]; pend &= ~(1u << k);
                        }
                }
            }
            __syncthreads();

            // ---- phase 2: gi MFMA (wv3-5) | coords out write (idx 0) ----
            if (wv >= 3 && wv < 6) {
                f32x4 c = {0.f, 0.f, 0.f, 0.f};
                #pragma unroll
                for (int kb = 0; kb < 16; ++kb) {
                    U8 a; a.q = *(const uint4*)(cbu + mn * 260 + kb * 16 + quad * 4);
                    c = __builtin_amdgcn_mfma_f32_16x16x32_bf16(a.s, bfrag[kb], c, 0, 0, 0);
                }
                #pragma unroll
                for (int reg = 0; reg < 4; ++reg)
                    gi_s[((quad * 4 + reg) * 16 + mn) * 3 + (wv - 3)] = c[reg];
            } else if (idx == 0 && t > 0 && tid < 48) {
                out[((size_t)(g * 16 + tid / 3) * 64 + (t - 1)) * 3 + tid % 3] = x_s[tid];
            }
            __syncthreads();

            // ---- gates + h update ----
            if (tid < 256) {
                const int ob = (gb * 16 + gd) * 3;
                const float x0 = x_s[gb * 3 + 0], x1 = x_s[gb * 3 + 1], x2 = x_s[gb * 3 + 2];
                const float giR = gi_s[ob + 0] + bih[0]
                                + x0 * wx_s[gd * 9 + 0] + x1 * wx_s[gd * 9 + 1] + x2 * wx_s[gd * 9 + 2];
                const float giZ = gi_s[ob + 1] + bih[1]
                                + x0 * wx_s[gd * 9 + 3] + x1 * wx_s[gd * 9 + 4] + x2 * wx_s[gd * 9 + 5];
                const float giN = gi_s[ob + 2] + bih[2]
                                + x0 * wx_s[gd * 9 + 6] + x1 * wx_s[gd * 9 + 7] + x2 * wx_s[gd * 9 + 8];
                const float ghR = gh_s[ob + 0] + bhh[0];
                const float ghZ = gh_s[ob + 1] + bhh[1];
                const float ghN = gh_s[ob + 2] + bhh[2];
                const float rg = sigm_f(giR + ghR);
                const float zg = sigm_f(giZ + ghZ);
                const float ng = tanh5(giN + rg * ghN);
                const float hnew = (1.f - zg) * ng + zg * hold;
                hold = hnew;
                const float s1 = __shfl_down(hnew, 1);
                const float s2 = __shfl_down(hnew, 2);
                const float s3 = __shfl_down(hnew, 3);
                if ((gd & 3) == 0)
                    cstore64(HxW + gb * 128 + ((d0 + gd) >> 2),
                             (u64)packbf2(hnew, s1) | ((u64)packbf2(s2, s3) << 32));
                if (t == 63)
                    out[OFF_OUT_HT + (size_t)(g * 16 + gb) * 512 + d0 + gd] = hnew;
            }
            __syncthreads();
            if (tid == 0) cstore32(FH + idx * 16, (u32)(t + 1));
        }

        // ---- final: coords(h_64) -> out[:,63] ----
        if (tid < 32) { const u32* f = FH + tid * 16; while (cload32(f) < 64u) {} }
        __syncthreads();
        #pragma unroll
        for (int u = 0; u < 4; ++u) {
            const int i = tid + 512 * u;
            const u64 v = cload64(HX + i);   // slot 0 holds h_64
            *(u64*)(hbu + (i >> 7) * 260 + (i & 127) * 2) = v;
        }
        __syncthreads();
        if (wv >= 6) {
            const int tt = tid - 384, cb = tt >> 3, kl = tt & 7;
            float a0 = 0.f, a1 = 0.f, a2 = 0.f;
            #pragma unroll 4
            for (int c = 0; c < 32; ++c) {
                const int p = kl * 32 + c;
                const float2 hv = unpackbf2(hbu[cb * 260 + p]);
                const float* w0 = wo_s + 2 * p * 3;
                a0 = fmaf(hv.x, w0[0], fmaf(hv.y, w0[3], a0));
                a1 = fmaf(hv.x, w0[1], fmaf(hv.y, w0[4], a1));
                a2 = fmaf(hv.x, w0[2], fmaf(hv.y, w0[5], a2));
            }
            a0 += __shfl_xor(a0, 1); a1 += __shfl_xor(a1, 1); a2 += __shfl_xor(a2, 1);
            a0 += __shfl_xor(a0, 2); a1 += __shfl_xor(a1, 2); a2 += __shfl_xor(a2, 2);
            a0 += __shfl_xor(a0, 4); a1 += __shfl_xor(a1, 4); a2 += __shfl_xor(a2, 4);
            if (kl == 0) {
                x_s[cb * 3 + 0] = a0 + wo_s[1536];
                x_s[cb * 3 + 1] = a1 + wo_s[1537];
                x_s[cb * 3 + 2] = a2 + wo_s[1538];
            }
        }
        __syncthreads();
        if (idx == 0 && tid < 48)
            out[((size_t)(g * 16 + tid / 3) * 64 + 63) * 3 + tid % 3] = x_s[tid];
    }
}

extern "C" void kernel_launch(void* const* d_in, const int* in_sizes, int n_in,
                              void* d_out, int out_size, void* d_ws, size_t ws_size,
                              hipStream_t stream) {
    const float* e_all  = (const float*)d_in[0];
    const float* e_last = (const float*)d_in[1];
    const float* Wa_w   = (const float*)d_in[2];
    const float* Wa_b   = (const float*)d_in[3];
    const float* Ua_w   = (const float*)d_in[4];
    const float* Ua_b   = (const float*)d_in[5];
    const float* Va_w   = (const float*)d_in[6];
    const float* W_ih   = (const float*)d_in[8];
    const float* W_hh   = (const float*)d_in[9];
    const float* b_ih   = (const float*)d_in[10];
    const float* b_hh   = (const float*)d_in[11];
    const float* Wo_w   = (const float*)d_in[12];
    const float* Wo_b   = (const float*)d_in[13];
    float* outp = (float*)d_out;
    float* ws   = (float*)d_ws;

    hipFuncSetAttribute((const void*)prep_kernel,
                        hipFuncAttributeMaxDynamicSharedMemorySize, PREP_LDS);
    hipFuncSetAttribute((const void*)decode_kernel,
                        hipFuncAttributeMaxDynamicSharedMemorySize, DYN_LDS);

    hipLaunchKernelGGL(prep_kernel, dim3(1024), dim3(256), PREP_LDS, stream,
                       e_all, e_last, Ua_w, Ua_b, ws);

    void* args[] = { (void*)&e_all, (void*)&e_last, (void*)&Wa_w, (void*)&Wa_b,
                     (void*)&Va_w,
                     (void*)&W_ih, (void*)&W_hh, (void*)&b_ih, (void*)&b_hh,
                     (void*)&Wo_w, (void*)&Wo_b, (void*)&outp, (void*)&ws };
    hipError_t err = hipLaunchCooperativeKernel((void*)decode_kernel, dim3(NBLK), dim3(NTHR),
                                                args, DYN_LDS, stream);
    if (err != hipSuccess) {
        // fallback: 192 blocks x 142KB LDS -> 1 block/CU, co-resident on 256 CUs
        hipLaunchKernelGGL(decode_kernel, dim3(NBLK), dim3(NTHR), DYN_LDS, stream,
                           e_all, e_last, Wa_w, Wa_b, Va_w,
                           W_ih, W_hh, b_ih, b_hh, Wo_w, Wo_b, outp, ws);
    }
}

// Round 13
// 832.426 us; speedup vs baseline: 1.3418x; 1.0081x over previous
//
#include <hip/hip_runtime.h>

typedef unsigned int u32;
typedef unsigned long long u64;
typedef float f32x4 __attribute__((ext_vector_type(4)));
typedef short short8 __attribute__((ext_vector_type(8)));

// B=64, S=128, D=512, T=64. 4 groups x 16 batches. All hops tagged (no flags).
// ws byte offsets:
#define OFF_UKB 0u          // u32[64*128*256] bf16 Uk
#define OFF_QX  16777216u   // u64[4 groups][2 slots][16 b][512] tagged f32 EQ (131072 B/group)
#define OFF_EX  17563648u   // per-group exchange
#define G_BYTES 131072u
// group layout: HX u64[2][4096] @0 (tagged {t|2bf16}) | CX u64[2][4096] @65536 (tagged {t|2bf16})

#define OFF_OUT_HT  12288u
#define OFF_OUT_ATT 45056u

#define NBLK 192
#define NTHR 512
#define DYN_LDS 145408
#define PREP_LDS 36864

__device__ __forceinline__ float fast_rcp(float x) { return __builtin_amdgcn_rcpf(x); }
// tanh = 1 - 2/(e^{2x}+1): graceful at +/-inf (rcp(inf)=0), no clamps needed
__device__ __forceinline__ float tanh5(float x) {
    float e = __expf(2.f * x);
    return 1.f - 2.f * fast_rcp(e + 1.f);
}
__device__ __forceinline__ float sigm_f(float x) { return fast_rcp(1.f + __expf(-x)); }

__device__ __forceinline__ u32 packbf2(float a, float b) {
    u32 ua = __float_as_uint(a); ua += 0x7FFFu + ((ua >> 16) & 1u);
    u32 ub = __float_as_uint(b); ub += 0x7FFFu + ((ub >> 16) & 1u);
    return (ua >> 16) | (ub & 0xFFFF0000u);
}
__device__ __forceinline__ float2 unpackbf2(u32 u) {
    return make_float2(__uint_as_float(u << 16), __uint_as_float(u & 0xFFFF0000u));
}
// split x into bf16-exact hi + residual lo (lo gets bf16-rounded later)
__device__ __forceinline__ float bf16hi(float x, float& lo) {
    u32 u = __float_as_uint(x); u += 0x7FFFu + ((u >> 16) & 1u); u &= 0xFFFF0000u;
    const float h = __uint_as_float(u); lo = x - h; return h;
}

// relaxed agent-scope accessors: per-access cache bypass, no cache-wide inv/wb
__device__ __forceinline__ u64 cload64(const u64* p) {
    return __hip_atomic_load(p, __ATOMIC_RELAXED, __HIP_MEMORY_SCOPE_AGENT);
}
__device__ __forceinline__ void cstore64(u64* p, u64 v) {
    __hip_atomic_store(p, v, __ATOMIC_RELAXED, __HIP_MEMORY_SCOPE_AGENT);
}

union U8 { u32 u[4]; uint4 q; short8 s; };

// ---------------- prep: Uk GEMM (MFMA, hi/lo bf16 split) + tagged H0 + HX/CX/QX reset ----------------
// grid 1024 x 256. GEMM tile: 64 rows x 64 cols, K=512 in 8 stages of 64 (36KB LDS -> 4 blk/CU).
__global__ __launch_bounds__(256) void prep_kernel(
    const float* __restrict__ e_all, const float* __restrict__ e_last,
    const float* __restrict__ Ua_w,  const float* __restrict__ Ua_b,
    float* __restrict__ ws)
{
    extern __shared__ char pls[];
    u32* Ahi = (u32*)pls;            // [64 rows][36 kp]
    u32* Alo = Ahi + 64 * 36;
    u32* Bhi = Alo + 64 * 36;        // [64 cols][36 kp]
    u32* Blo = Bhi + 64 * 36;

    u32* UKB = (u32*)((char*)ws + OFF_UKB);

    const int blk = blockIdx.x, tid = threadIdx.x;
    const int gtid = blk * 256 + tid, gstride = 1024 * 256;

    // HX slot 1 zero (tag 0; readers of slot 1 want odd tags >= 1)
    for (int i = gtid; i < 16384; i += gstride) {
        const int g = i >> 12, j = i & 4095;
        ((u64*)((char*)ws + OFF_EX + (size_t)g * G_BYTES))[4096 + j] = 0ull;
    }
    // CX zero (both slots; tag 0 != any step tag)
    for (int i = gtid; i < 32768; i += gstride) {
        const int g = i >> 13, j = i & 8191;
        ((u64*)((char*)ws + OFF_EX + (size_t)g * G_BYTES + 65536))[j] = 0ull;
    }
    // QX zero
    for (int i = gtid; i < 65536; i += gstride)
        ((u64*)((char*)ws + OFF_QX))[i] = 0ull;
    // H0 -> HX slot 0, tagged 0 (fully written -> tag-0 want at t=0 is safe)
    for (int i = gtid; i < 16384; i += gstride) {
        const int g = i >> 12, i2 = i & 4095;
        const int b = i2 >> 8, pr = i2 & 255;
        const float* ep = e_last + ((size_t)(g * 16 + b) * 512) + 2 * pr;
        u64* HXg = (u64*)((char*)ws + OFF_EX + (size_t)g * G_BYTES);
        HXg[i2] = (u64)packbf2(ep[0], ep[1]);   // tag 0 in high bits
    }

    // ---- Uk = e_all[8192x512] @ Ua[512x512] + b, MFMA with hi+lo compensation ----
    const int r0 = (blk >> 3) * 64, c0 = (blk & 7) * 64;
    const int lane = tid & 63, wv = tid >> 6;
    const int mn = lane & 15, quad = lane >> 4;

    f32x4 acc[4];
    #pragma unroll
    for (int rg = 0; rg < 4; ++rg) acc[rg] = (f32x4){0.f, 0.f, 0.f, 0.f};

    for (int ks = 0; ks < 8; ++ks) {
        if (ks) __syncthreads();   // protect LDS reuse across stages
        // stage A: 64 rows x 16 float4 (k = ks*64 .. +63)
        for (int i = tid; i < 1024; i += 256) {
            const int row = i >> 4, q4i = i & 15;
            const float4 e = *(const float4*)(e_all + (size_t)(r0 + row) * 512 + ks * 64 + 4 * q4i);
            float l0, l1, l2, l3;
            const float h0 = bf16hi(e.x, l0), h1 = bf16hi(e.y, l1);
            const float h2 = bf16hi(e.z, l2), h3 = bf16hi(e.w, l3);
            Ahi[row * 36 + 2 * q4i]     = packbf2(h0, h1);
            Ahi[row * 36 + 2 * q4i + 1] = packbf2(h2, h3);
            Alo[row * 36 + 2 * q4i]     = packbf2(l0, l1);
            Alo[row * 36 + 2 * q4i + 1] = packbf2(l2, l3);
        }
        // stage B: 32 kp x 64 cols
        for (int i = tid; i < 2048; i += 256) {
            const int col = i & 63, kp = i >> 6;
            const float b0 = Ua_w[(size_t)(ks * 64 + 2 * kp) * 512 + c0 + col];
            const float b1 = Ua_w[(size_t)(ks * 64 + 2 * kp + 1) * 512 + c0 + col];
            float l0, l1;
            const float h0 = bf16hi(b0, l0), h1 = bf16hi(b1, l1);
            Bhi[col * 36 + kp] = packbf2(h0, h1);
            Blo[col * 36 + kp] = packbf2(l0, l1);
        }
        __syncthreads();
        #pragma unroll
        for (int kb = 0; kb < 2; ++kb) {
            const int fo = kb * 16 + quad * 4;
            U8 bh, bl;
            bh.q = *(const uint4*)(Bhi + (wv * 16 + mn) * 36 + fo);
            bl.q = *(const uint4*)(Blo + (wv * 16 + mn) * 36 + fo);
            #pragma unroll
            for (int rg = 0; rg < 4; ++rg) {
                U8 ah, al;
                ah.q = *(const uint4*)(Ahi + (rg * 16 + mn) * 36 + fo);
                al.q = *(const uint4*)(Alo + (rg * 16 + mn) * 36 + fo);
                acc[rg] = __builtin_amdgcn_mfma_f32_16x16x32_bf16(al.s, bh.s, acc[rg], 0, 0, 0);
                acc[rg] = __builtin_amdgcn_mfma_f32_16x16x32_bf16(ah.s, bl.s, acc[rg], 0, 0, 0);
                acc[rg] = __builtin_amdgcn_mfma_f32_16x16x32_bf16(ah.s, bh.s, acc[rg], 0, 0, 0);
            }
        }
    }
    // epilogue: bias + pack pairs (cols mn,mn+1 via shfl) + store
    const int col = c0 + wv * 16 + mn;
    const float bias = Ua_b[col];
    #pragma unroll
    for (int rg = 0; rg < 4; ++rg) {
        #pragma unroll
        for (int reg = 0; reg < 4; ++reg) {
            const float v = acc[rg][reg] + bias;
            const float v1 = __shfl_down(v, 1);
            if (!(mn & 1))
                UKB[(size_t)(r0 + rg * 16 + quad * 4 + reg) * 256 + (col >> 1)] = packbf2(v, v1);
        }
    }
}

// ---------------- persistent decode: per group 16 attn + 32 GRU blocks ----------------
__global__ __launch_bounds__(512, 1) void decode_kernel(
    const float* __restrict__ e_all,
    const float* __restrict__ e_last,
    const float* __restrict__ Wa_w,  const float* __restrict__ Wa_b,
    const float* __restrict__ Va_w,
    const float* __restrict__ W_ih,  const float* __restrict__ W_hh,
    const float* __restrict__ b_ih,  const float* __restrict__ b_hh,
    const float* __restrict__ Wo_w,  const float* __restrict__ Wo_b,
    float* __restrict__ out, float* __restrict__ ws)
{
    extern __shared__ char smraw[];

    const u32* UKB = (const u32*)((char*)ws + OFF_UKB);

    const int tid = threadIdx.x;
    const int bi  = blockIdx.x;
    const int g   = bi / 48, r = bi % 48;
    const int lane = tid & 63, wv = tid >> 6;

    char* gbase = (char*)ws + OFF_EX + (size_t)g * G_BYTES;
    u64* HX = (u64*)gbase;             // [2 slots][4096] tagged
    u64* CX = (u64*)(gbase + 65536);   // [2 slots][4096] tagged

    if (r < 16) {
        // ===================== attention block: one per b =====================
        // EU = exp(2*Uk) in LDS; EQ arrives tagged; ctx leaves tagged (no drain, no flag).
        // tanh(q+Uk) = 1 - 2*rcp(EQ*EU + 1); score = vaSum + sum (-2Va)*rcp(...). No max-sub.
        const int bl = r, b = g * 16 + bl;
        u32*   EuL  = (u32*)smraw;                 // 131072 B: exp(2*Uk[b]) bf16 [128 s][256 pairs]
        float* eq_s = (float*)(smraw + 131072);    // 512 f32: exp(2*q)
        float* w_s  = (float*)(smraw + 133120);    // 128 (raw exp)
        float* red  = (float*)(smraw + 133632);    // 16
        float* psq  = (float*)(smraw + 133696);    // 8192 B: ctx partials

        const u64* QXR = (const u64*)((char*)ws + OFF_QX + (size_t)g * 131072u);

        // stage EU = exp(2*Uk[b]) into LDS once (persistent across all 64 steps)
        {
            const uint4* src = (const uint4*)(UKB + (size_t)b * 32768);
            uint4* dst = (uint4*)EuL;
            #pragma unroll
            for (int i = 0; i < 16; ++i) {
                uint4 u = src[tid + 512 * i];
                float2 p;
                p = unpackbf2(u.x); u.x = packbf2(__expf(2.f * p.x), __expf(2.f * p.y));
                p = unpackbf2(u.y); u.y = packbf2(__expf(2.f * p.x), __expf(2.f * p.y));
                p = unpackbf2(u.z); u.z = packbf2(__expf(2.f * p.x), __expf(2.f * p.y));
                p = unpackbf2(u.w); u.w = packbf2(__expf(2.f * p.x), __expf(2.f * p.y));
                dst[tid + 512 * i] = u;
            }
        }
        // E[b] slice into registers once (bf16-packed from f32 e_all)
        uint2 ereg[32];
        {
            const int dq = tid & 127, sg = tid >> 7;
            const float* ep = e_all + (size_t)b * 65536;
            #pragma unroll
            for (int si = 0; si < 32; ++si) {
                const float4 e = *(const float4*)(ep + (size_t)(sg * 32 + si) * 512 + 4 * dq);
                ereg[si] = make_uint2(packbf2(e.x, e.y), packbf2(e.z, e.w));
            }
        }
        // Va-derived constants: va2 = -2*Va slices, vaSum = sum over my 32 dims
        const int kl = lane & 15;
        float4 va2a[4], va2b[4];
        float vaSum = 0.f;
        #pragma unroll
        for (int it = 0; it < 4; ++it) {
            const float4 a  = *(const float4*)(Va_w + (it * 16 + kl) * 8);
            const float4 b2 = *(const float4*)(Va_w + (it * 16 + kl) * 8 + 4);
            vaSum += a.x + a.y + a.z + a.w + b2.x + b2.y + b2.z + b2.w;
            va2a[it] = make_float4(-2.f * a.x,  -2.f * a.y,  -2.f * a.z,  -2.f * a.w);
            va2b[it] = make_float4(-2.f * b2.x, -2.f * b2.y, -2.f * b2.z, -2.f * b2.w);
        }
        __syncthreads();

        for (int t = 0; t < 64; ++t) {
            const int slot = t & 1;
            const u32 tg = (u32)(t + 1);
            u64* CxS = CX + slot * 4096;
            const u64* QxS = QXR + slot * 8192 + (size_t)bl * 512;

            // tagged EQ: each of tid<256 spins on its own 2 words (data IS the signal)
            if (tid < 256) {
                u64 v0 = cload64(QxS + 2 * tid), v1 = cload64(QxS + 2 * tid + 1);
                while ((u32)(v0 >> 32) != tg) v0 = cload64(QxS + 2 * tid);
                while ((u32)(v1 >> 32) != tg) v1 = cload64(QxS + 2 * tid + 1);
                ((float2*)eq_s)[tid] = make_float2(__uint_as_float((u32)v0),
                                                   __uint_as_float((u32)v1));
            }
            __syncthreads();

            // ---- scores: vaSum + sum va2*rcp(EQ*EU+1), then exp ----
            {
                float4 eqa[4], eqb[4];
                const float4* q4 = (const float4*)eq_s;
                #pragma unroll
                for (int it = 0; it < 4; ++it) {
                    eqa[it] = q4[(it * 16 + kl) * 2];  eqb[it] = q4[(it * 16 + kl) * 2 + 1];
                }
                const int sbase = wv * 16 + (lane >> 4);
                #pragma unroll
                for (int sg = 0; sg < 4; ++sg) {
                    const int s = sbase + sg * 4;
                    const uint4* uk4 = (const uint4*)EuL + (size_t)s * 64;
                    float acc = vaSum;
                    #pragma unroll
                    for (int it = 0; it < 4; ++it) {
                        const uint4 u = uk4[it * 16 + kl];
                        const float2 u0 = unpackbf2(u.x), u1 = unpackbf2(u.y);
                        const float2 u2 = unpackbf2(u.z), u3 = unpackbf2(u.w);
                        acc = fmaf(va2a[it].x, fast_rcp(fmaf(eqa[it].x, u0.x, 1.f)), acc);
                        acc = fmaf(va2a[it].y, fast_rcp(fmaf(eqa[it].y, u0.y, 1.f)), acc);
                        acc = fmaf(va2a[it].z, fast_rcp(fmaf(eqa[it].z, u1.x, 1.f)), acc);
                        acc = fmaf(va2a[it].w, fast_rcp(fmaf(eqa[it].w, u1.y, 1.f)), acc);
                        acc = fmaf(va2b[it].x, fast_rcp(fmaf(eqb[it].x, u2.x, 1.f)), acc);
                        acc = fmaf(va2b[it].y, fast_rcp(fmaf(eqb[it].y, u2.y, 1.f)), acc);
                        acc = fmaf(va2b[it].z, fast_rcp(fmaf(eqb[it].z, u3.x, 1.f)), acc);
                        acc = fmaf(va2b[it].w, fast_rcp(fmaf(eqb[it].w, u3.y, 1.f)), acc);
                    }
                    acc += __shfl_xor(acc, 1); acc += __shfl_xor(acc, 2);
                    acc += __shfl_xor(acc, 4); acc += __shfl_xor(acc, 8);
                    if (kl == 0) w_s[s] = __expf(acc);   // Va_b: softmax-invariant
                }
            }
            __syncthreads();

            // ---- denom (wave0) overlapped with unnormalized ctx accum from regs (all) ----
            if (tid < 64) {
                float sm = w_s[tid] + w_s[tid + 64];
                #pragma unroll
                for (int off = 32; off > 0; off >>= 1) sm += __shfl_down(sm, off);
                if (tid == 0) red[1] = fast_rcp(sm);
            }
            {
                const int dq = tid & 127, sg = tid >> 7;
                float4 a = {0.f, 0.f, 0.f, 0.f};
                #pragma unroll
                for (int si = 0; si < 32; ++si) {
                    const float wgt = w_s[sg * 32 + si];
                    const float2 e0 = unpackbf2(ereg[si].x), e1 = unpackbf2(ereg[si].y);
                    a.x = fmaf(wgt, e0.x, a.x);
                    a.y = fmaf(wgt, e0.y, a.y);
                    a.z = fmaf(wgt, e1.x, a.z);
                    a.w = fmaf(wgt, e1.y, a.w);
                }
                ((float4*)psq)[sg * 128 + dq] = a;
            }
            __syncthreads();
            if (tid < 128) {
                const float rn = red[1];
                const float4* p4 = (const float4*)psq;
                float4 a = p4[tid], b2 = p4[128 + tid], c2 = p4[256 + tid], d2 = p4[384 + tid];
                const float rx = (a.x + b2.x + c2.x + d2.x) * rn;
                const float ry = (a.y + b2.y + c2.y + d2.y) * rn;
                const float rz = (a.z + b2.z + c2.z + d2.z) * rn;
                const float rw = (a.w + b2.w + c2.w + d2.w) * rn;
                const u64 tg64 = (u64)tg << 32;
                cstore64(CxS + (size_t)bl * 256 + 2 * tid,     tg64 | (u64)packbf2(rx, ry));
                cstore64(CxS + (size_t)bl * 256 + 2 * tid + 1, tg64 | (u64)packbf2(rz, rw));
            } else if (tid < 256) {   // ATT write, same phase (red/w_s ready; barrier-free tail)
                out[OFF_OUT_ATT + ((size_t)b * 64 + t) * 128 + (tid - 128)] = w_s[tid - 128] * red[1];
            }
            // no trailing barrier: next-iter EQ barrier orders w_s/red/psq reuse
        }
    } else {
        // ========== GRU block: 16 dims, 16 b, MFMA tiles, weights in B-frag regs ==========
        // all hops tagged: h staged via round-spin; ctx via round-spin; EQ published tagged.
        const int idx = r - 16, d0 = idx * 16;
        u32*   hbu  = (u32*)smraw;                  // [16][260] bf16-pairs (padded)
        u32*   cbu  = (u32*)(smraw + 16640);        // [16][260] ctx staging
        float* gh_s = (float*)(smraw + 33280);      // 768
        float* gi_s = (float*)(smraw + 36352);      // 768
        float* x_s  = (float*)(smraw + 39424);      // 48
        float* wx_s = (float*)(smraw + 39616);      // 144
        float* wo_s = (float*)(smraw + 40192);      // 1536 + 3

        u64* QXW = (u64*)((char*)ws + OFF_QX + (size_t)g * 131072u);

        const int mn = lane & 15, quad = lane >> 4;

        // ---- B-fragments: wv 0-2 = gh gates R,Z,N; wv 3-5 = gi gates; wv 6 = Wa cols ----
        short8 bfrag[16];
        float qbias = 0.f;
        if (wv < 3) {
            const float* wrow = W_hh + (size_t)(wv * 512 + d0 + mn) * 512;
            #pragma unroll
            for (int kb = 0; kb < 16; ++kb) {
                const int k0 = kb * 32 + quad * 8;
                U8 tpk;
                #pragma unroll
                for (int c = 0; c < 4; ++c)
                    tpk.u[c] = packbf2(wrow[k0 + 2 * c], wrow[k0 + 2 * c + 1]);
                bfrag[kb] = tpk.s;
            }
        } else if (wv < 6) {
            const float* wrow = W_ih + (size_t)((wv - 3) * 512 + d0 + mn) * 515;
            #pragma unroll
            for (int kb = 0; kb < 16; ++kb) {
                const int k0 = kb * 32 + quad * 8;
                U8 tpk;
                #pragma unroll
                for (int c = 0; c < 4; ++c)
                    tpk.u[c] = packbf2(wrow[k0 + 2 * c], wrow[k0 + 2 * c + 1]);
                bfrag[kb] = tpk.s;
            }
        } else if (wv == 6) {
            // B[k][col=d0+mn] = Wa_w[k][d0+mn]
            #pragma unroll
            for (int kb = 0; kb < 16; ++kb) {
                const int k0 = kb * 32 + quad * 8;
                U8 tpk;
                #pragma unroll
                for (int c = 0; c < 4; ++c)
                    tpk.u[c] = packbf2(Wa_w[(size_t)(k0 + 2 * c) * 512 + d0 + mn],
                                       Wa_w[(size_t)(k0 + 2 * c + 1) * 512 + d0 + mn]);
                bfrag[kb] = tpk.s;
            }
            qbias = Wa_b[d0 + mn];
        }
        if (tid < 144) {
            const int dd = tid / 9, rem = tid - dd * 9, g3 = rem / 3, c = rem - g3 * 3;
            wx_s[tid] = W_ih[(size_t)(g3 * 512 + d0 + dd) * 515 + 512 + c];
        }
        for (int i = tid; i < 1536; i += 512) wo_s[i] = Wo_w[i];
        if (tid < 3) wo_s[1536 + tid] = Wo_b[tid];

        const int gb = tid >> 4, gd = tid & 15;     // gates mapping (tid<256)
        float hold = 0.f, bih[3], bhh[3];
        if (tid < 256) {
            hold = e_last[(size_t)(g * 16 + gb) * 512 + d0 + gd];
            #pragma unroll
            for (int g3 = 0; g3 < 3; ++g3) {
                bih[g3] = b_ih[g3 * 512 + d0 + gd];
                bhh[g3] = b_hh[g3 * 512 + d0 + gd];
            }
        }

        for (int t = 0; t < 64; ++t) {
            const int slot = t & 1;
            const u32 tg = (u32)(t + 1);
            const u64* HxS = HX + slot * 4096;
            const u64* CxS = CX + slot * 4096;
            u64* HxW = HX + ((t + 1) & 1) * 4096;

            // tagged h stage: 8 words/thread, round-based verify (h_t carries tag t)
            {
                const u32 htag = (u32)t;
                u64 hh[8];
                u32 pend = 0xFFu;
                #pragma unroll
                for (int k = 0; k < 8; ++k) hh[k] = cload64(HxS + tid + 512 * k);
                #pragma unroll
                for (int k = 0; k < 8; ++k)
                    if ((u32)(hh[k] >> 32) == htag) {
                        const int i = tid + 512 * k;
                        hbu[(i >> 8) * 260 + (i & 255)] = (u32)hh[k];
                        pend &= ~(1u << k);
                    }
                while (pend) {
                    #pragma unroll
                    for (int k = 0; k < 8; ++k)
                        if (pend & (1u << k)) hh[k] = cload64(HxS + tid + 512 * k);
                    #pragma unroll
                    for (int k = 0; k < 8; ++k)
                        if ((pend & (1u << k)) && (u32)(hh[k] >> 32) == htag) {
                            const int i = tid + 512 * k;
                            hbu[(i >> 8) * 260 + (i & 255)] = (u32)hh[k];
                            pend &= ~(1u << k);
                        }
                }
            }
            __syncthreads();

            // ---- phase 1: gh (wv0-2) | ctx round-spin (wv3-6; wv6 q+EQ first) | coords (wv7)
            if (wv < 3) {
                f32x4 c = {0.f, 0.f, 0.f, 0.f};
                #pragma unroll
                for (int kb = 0; kb < 16; ++kb) {
                    U8 a; a.q = *(const uint4*)(hbu + mn * 260 + kb * 16 + quad * 4);
                    c = __builtin_amdgcn_mfma_f32_16x16x32_bf16(a.s, bfrag[kb], c, 0, 0, 0);
                }
                #pragma unroll
                for (int reg = 0; reg < 4; ++reg)
                    gh_s[((quad * 4 + reg) * 16 + mn) * 3 + wv] = c[reg];
            } else if (wv == 7) {
                const int tt = tid - 448, cb = tt >> 2, kl = tt & 3;
                if (t > 0) {
                    float a0 = 0.f, a1 = 0.f, a2 = 0.f;
                    #pragma unroll 4
                    for (int c = 0; c < 64; ++c) {
                        const int p = kl * 64 + c;
                        const float2 hv = unpackbf2(hbu[cb * 260 + p]);
                        const float* w0 = wo_s + 2 * p * 3;
                        a0 = fmaf(hv.x, w0[0], fmaf(hv.y, w0[3], a0));
                        a1 = fmaf(hv.x, w0[1], fmaf(hv.y, w0[4], a1));
                        a2 = fmaf(hv.x, w0[2], fmaf(hv.y, w0[5], a2));
                    }
                    a0 += __shfl_xor(a0, 1); a1 += __shfl_xor(a1, 1); a2 += __shfl_xor(a2, 1);
                    a0 += __shfl_xor(a0, 2); a1 += __shfl_xor(a1, 2); a2 += __shfl_xor(a2, 2);
                    if (kl == 0) {
                        x_s[cb * 3 + 0] = a0 + wo_s[1536];
                        x_s[cb * 3 + 1] = a1 + wo_s[1537];
                        x_s[cb * 3 + 2] = a2 + wo_s[1538];
                    }
                } else if (tt < 48) x_s[tt] = 0.f;
            } else {
                // waves 3-6: wv6 publishes tagged EQ first, then all join ctx staging
                if (wv == 6) {
                    f32x4 c = {0.f, 0.f, 0.f, 0.f};
                    #pragma unroll
                    for (int kb = 0; kb < 16; ++kb) {
                        U8 a; a.q = *(const uint4*)(hbu + mn * 260 + kb * 16 + quad * 4);
                        c = __builtin_amdgcn_mfma_f32_16x16x32_bf16(a.s, bfrag[kb], c, 0, 0, 0);
                    }
                    u64* QxW = QXW + slot * 8192;
                    const u64 tg64 = (u64)tg << 32;
                    #pragma unroll
                    for (int reg = 0; reg < 4; ++reg) {
                        const float q0 = c[reg] + qbias;
                        const float e  = __expf(2.f * q0);
                        cstore64(QxW + (size_t)(quad * 4 + reg) * 512 + d0 + mn,
                                 tg64 | (u64)__float_as_uint(e));
                    }
                }
                // tagged ctx stage: thread thr spins col=thr across b=0..15, round-based
                const int thr = (wv - 3) * 64 + lane;   // 0..255
                u64 cc[16];
                u32 pend = 0xFFFFu;
                #pragma unroll
                for (int k = 0; k < 16; ++k) cc[k] = cload64(CxS + thr + 256 * k);
                #pragma unroll
                for (int k = 0; k < 16; ++k)
                    if ((u32)(cc[k] >> 32) == tg) { cbu[k * 260 + thr] = (u32)cc[k]; pend &= ~(1u << k); }
                while (pend) {
                    #pragma unroll
                    for (int k = 0; k < 16; ++k)
                        if (pend & (1u << k)) cc[k] = cload64(CxS + thr + 256 * k);
                    #pragma unroll
                    for (int k = 0; k < 16; ++k)
                        if ((pend & (1u << k)) && (u32)(cc[k] >> 32) == tg) {
                            cbu[k * 260 + thr] = (u32)cc[k]; pend &= ~(1u << k);
                        }
                }
            }
            __syncthreads();

            // ---- phase 2: gi MFMA (wv3-5) | coords out write (idx 0) ----
            if (wv >= 3 && wv < 6) {
                f32x4 c = {0.f, 0.f, 0.f, 0.f};
                #pragma unroll
                for (int kb = 0; kb < 16; ++kb) {
                    U8 a; a.q = *(const uint4*)(cbu + mn * 260 + kb * 16 + quad * 4);
                    c = __builtin_amdgcn_mfma_f32_16x16x32_bf16(a.s, bfrag[kb], c, 0, 0, 0);
                }
                #pragma unroll
                for (int reg = 0; reg < 4; ++reg)
                    gi_s[((quad * 4 + reg) * 16 + mn) * 3 + (wv - 3)] = c[reg];
            } else if (idx == 0 && t > 0 && tid < 48) {
                out[((size_t)(g * 16 + tid / 3) * 64 + (t - 1)) * 3 + tid % 3] = x_s[tid];
            }
            __syncthreads();

            // ---- gates + h update; tagged HX stores (no drain, no flag, no barrier) ----
            if (tid < 256) {
                const int ob = (gb * 16 + gd) * 3;
                const float x0 = x_s[gb * 3 + 0], x1 = x_s[gb * 3 + 1], x2 = x_s[gb * 3 + 2];
                const float giR = gi_s[ob + 0] + bih[0]
                                + x0 * wx_s[gd * 9 + 0] + x1 * wx_s[gd * 9 + 1] + x2 * wx_s[gd * 9 + 2];
                const float giZ = gi_s[ob + 1] + bih[1]
                                + x0 * wx_s[gd * 9 + 3] + x1 * wx_s[gd * 9 + 4] + x2 * wx_s[gd * 9 + 5];
                const float giN = gi_s[ob + 2] + bih[2]
                                + x0 * wx_s[gd * 9 + 6] + x1 * wx_s[gd * 9 + 7] + x2 * wx_s[gd * 9 + 8];
                const float ghR = gh_s[ob + 0] + bhh[0];
                const float ghZ = gh_s[ob + 1] + bhh[1];
                const float ghN = gh_s[ob + 2] + bhh[2];
                const float rg = sigm_f(giR + ghR);
                const float zg = sigm_f(giZ + ghZ);
                const float ng = tanh5(giN + rg * ghN);
                const float hnew = (1.f - zg) * ng + zg * hold;
                hold = hnew;
                const float s1 = __shfl_down(hnew, 1);
                if ((gd & 1) == 0)
                    cstore64(HxW + (size_t)gb * 256 + ((d0 + gd) >> 1),
                             ((u64)tg << 32) | (u64)packbf2(hnew, s1));
                if (t == 63)
                    out[OFF_OUT_HT + (size_t)(g * 16 + gb) * 512 + d0 + gd] = hnew;
            }
            // no trailing barrier: next-iter staging barrier orders LDS reuse
        }

        // ---- final: coords(h_64, tag 64 in HX slot 0) -> out[:,63] ----
        {
            u64 hh[8];
            u32 pend = 0xFFu;
            #pragma unroll
            for (int k = 0; k < 8; ++k) hh[k] = cload64(HX + tid + 512 * k);
            #pragma unroll
            for (int k = 0; k < 8; ++k)
                if ((u32)(hh[k] >> 32) == 64u) {
                    const int i = tid + 512 * k;
                    hbu[(i >> 8) * 260 + (i & 255)] = (u32)hh[k];
                    pend &= ~(1u << k);
                }
            while (pend) {
                #pragma unroll
                for (int k = 0; k < 8; ++k)
                    if (pend & (1u << k)) hh[k] = cload64(HX + tid + 512 * k);
                #pragma unroll
                for (int k = 0; k < 8; ++k)
                    if ((pend & (1u << k)) && (u32)(hh[k] >> 32) == 64u) {
                        const int i = tid + 512 * k;
                        hbu[(i >> 8) * 260 + (i & 255)] = (u32)hh[k];
                        pend &= ~(1u << k);
                    }
            }
        }
        __syncthreads();
        if (wv >= 6) {
            const int tt = tid - 384, cb = tt >> 3, kl = tt & 7;
            float a0 = 0.f, a1 = 0.f, a2 = 0.f;
            #pragma unroll 4
            for (int c = 0; c < 32; ++c) {
                const int p = kl * 32 + c;
                const float2 hv = unpackbf2(hbu[cb * 260 + p]);
                const float* w0 = wo_s + 2 * p * 3;
                a0 = fmaf(hv.x, w0[0], fmaf(hv.y, w0[3], a0));
                a1 = fmaf(hv.x, w0[1], fmaf(hv.y, w0[4], a1));
                a2 = fmaf(hv.x, w0[2], fmaf(hv.y, w0[5], a2));
            }
            a0 += __shfl_xor(a0, 1); a1 += __shfl_xor(a1, 1); a2 += __shfl_xor(a2, 1);
            a0 += __shfl_xor(a0, 2); a1 += __shfl_xor(a1, 2); a2 += __shfl_xor(a2, 2);
            a0 += __shfl_xor(a0, 4); a1 += __shfl_xor(a1, 4); a2 += __shfl_xor(a2, 4);
            if (kl == 0) {
                x_s[cb * 3 + 0] = a0 + wo_s[1536];
                x_s[cb * 3 + 1] = a1 + wo_s[1537];
                x_s[cb * 3 + 2] = a2 + wo_s[1538];
            }
        }
        __syncthreads();
        if (idx == 0 && tid < 48)
            out[((size_t)(g * 16 + tid / 3) * 64 + 63) * 3 + tid % 3] = x_s[tid];
    }
}

extern "C" void kernel_launch(void* const* d_in, const int* in_sizes, int n_in,
                              void* d_out, int out_size, void* d_ws, size_t ws_size,
                              hipStream_t stream) {
    const float* e_all  = (const float*)d_in[0];
    const float* e_last = (const float*)d_in[1];
    const float* Wa_w   = (const float*)d_in[2];
    const float* Wa_b   = (const float*)d_in[3];
    const float* Ua_w   = (const float*)d_in[4];
    const float* Ua_b   = (const float*)d_in[5];
    const float* Va_w   = (const float*)d_in[6];
    const float* W_ih   = (const float*)d_in[8];
    const float* W_hh   = (const float*)d_in[9];
    const float* b_ih   = (const float*)d_in[10];
    const float* b_hh   = (const float*)d_in[11];
    const float* Wo_w   = (const float*)d_in[12];
    const float* Wo_b   = (const float*)d_in[13];
    float* outp = (float*)d_out;
    float* ws   = (float*)d_ws;

    hipFuncSetAttribute((const void*)prep_kernel,
                        hipFuncAttributeMaxDynamicSharedMemorySize, PREP_LDS);
    hipFuncSetAttribute((const void*)decode_kernel,
                        hipFuncAttributeMaxDynamicSharedMemorySize, DYN_LDS);

    hipLaunchKernelGGL(prep_kernel, dim3(1024), dim3(256), PREP_LDS, stream,
                       e_all, e_last, Ua_w, Ua_b, ws);

    void* args[] = { (void*)&e_all, (void*)&e_last, (void*)&Wa_w, (void*)&Wa_b,
                     (void*)&Va_w,
                     (void*)&W_ih, (void*)&W_hh, (void*)&b_ih, (void*)&b_hh,
                     (void*)&Wo_w, (void*)&Wo_b, (void*)&outp, (void*)&ws };
    hipError_t err = hipLaunchCooperativeKernel((void*)decode_kernel, dim3(NBLK), dim3(NTHR),
                                                args, DYN_LDS, stream);
    if (err != hipSuccess) {
        // fallback: 192 blocks x 142KB LDS -> 1 block/CU, co-resident on 256 CUs
        hipLaunchKernelGGL(decode_kernel, dim3(NBLK), dim3(NTHR), DYN_LDS, stream,
                           e_all, e_last, Wa_w, Wa_b, Va_w,
                           W_ih, W_hh, b_ih, b_hh, Wo_w, Wo_b, outp, ws);
    }
}